// Round 4
// baseline (1227.448 us; speedup 1.0000x reference)
//
#include <hip/hip_runtime.h>
#include <hip/hip_bf16.h>

#define NLAY 8
#define MFMA __builtin_amdgcn_mfma_f32_16x16x32_bf16
#define MFMA32 __builtin_amdgcn_mfma_f32_32x32x16_bf16

typedef __attribute__((ext_vector_type(8))) short bf16x8;
typedef __attribute__((ext_vector_type(4))) float f32x4;
typedef __attribute__((ext_vector_type(16))) float f32x16;
typedef __attribute__((ext_vector_type(4))) int i32x4;

template <bool BF16>
__device__ __forceinline__ float ld(const void* p, int i) {
  if (BF16) {
    unsigned short u = ((const unsigned short*)p)[i];
    return __uint_as_float(((unsigned)u) << 16);
  }
  return ((const float*)p)[i];
}

template <bool BF16>
__device__ __forceinline__ float2 ld2(const void* p, int i) {  // i even
  float2 r;
  if (BF16) {
    unsigned u = ((const unsigned*)p)[i >> 1];
    r.x = __uint_as_float(u << 16);
    r.y = __uint_as_float(u & 0xffff0000u);
  } else {
    r = ((const float2*)p)[i >> 1];
  }
  return r;
}

__device__ __forceinline__ float bfu(unsigned short u) {
  return __uint_as_float(((unsigned)u) << 16);
}

__device__ __forceinline__ unsigned pack_bf2(float a, float b) {
  __hip_bfloat16 ha = __float2bfloat16(a), hb = __float2bfloat16(b);
  unsigned short ua, ub;
  __builtin_memcpy(&ua, &ha, 2);
  __builtin_memcpy(&ub, &hb, 2);
  return ((unsigned)ub << 16) | (unsigned)ua;
}

__device__ __forceinline__ unsigned short cvt_bf(float a) {
  __hip_bfloat16 h = __float2bfloat16(a);
  unsigned short us;
  __builtin_memcpy(&us, &h, 2);
  return us;
}

__device__ __forceinline__ float2 unpk(unsigned u) {
  float2 r;
  r.x = __uint_as_float(u << 16);
  r.y = __uint_as_float(u & 0xffff0000u);
  return r;
}

__device__ __forceinline__ bf16x8 as_bf(i32x4 v) {
  bf16x8 r;
  __builtin_memcpy(&r, &v, 16);
  return r;
}

// 8 consecutive values starting at element i (i % 8 == 0)
template <bool BF16>
__device__ __forceinline__ void ld8v(const void* p, int i, float* v) {
  if (BF16) {
    i32x4 u = *(const i32x4*)((const unsigned short*)p + i);
    float2 a = unpk((unsigned)u.x); v[0] = a.x; v[1] = a.y;
    float2 b = unpk((unsigned)u.y); v[2] = b.x; v[3] = b.y;
    float2 c = unpk((unsigned)u.z); v[4] = c.x; v[5] = c.y;
    float2 d = unpk((unsigned)u.w); v[6] = d.x; v[7] = d.y;
  } else {
    float4 a = *(const float4*)((const float*)p + i);
    float4 b = *(const float4*)((const float*)p + i + 4);
    v[0] = a.x; v[1] = a.y; v[2] = a.z; v[3] = a.w;
    v[4] = b.x; v[5] = b.y; v[6] = b.z; v[7] = b.w;
  }
}

// ws[0..271]=sin, ws[272..543]=cos, ws[544..1699]=dmask, ws[1700]=dtype flag
__global__ void setup_tables(float* __restrict__ ws, const void* __restrict__ x) {
  int tid = threadIdx.x;
  for (int idx = tid; idx < 272; idx += 256) {
    int t = idx >> 4, j = idx & 15;
    float a = powf(10000.f, -(float)(j >> 1) / 7.f);
    float arg = (float)t * a;
    ws[idx] = sinf(arg);
    ws[272 + idx] = cosf(arg);
  }
  for (int row = tid; row < 68; row += 256) {
    int hh = row / 17, t = row % 17;
    float gamma = 1.f - exp2f(-5.f - 4.f * (float)hh / 3.f);
    float sum = 0.f;
    for (int u = 0; u <= t; ++u) sum += powf(gamma, (float)(t - u));
    float rn = rsqrtf(sum);
    for (int u = 0; u < 17; ++u)
      ws[544 + row * 17 + u] = (u <= t) ? powf(gamma, (float)(t - u)) * rn : 0.f;
  }
  if (tid == 0) {
    const unsigned short* u16 = (const unsigned short*)x;
    int sane = 0;
    for (int i = 0; i < 128; ++i) {
      float v = __uint_as_float(((unsigned)u16[2 * i]) << 16);
      float av = fabsf(v);
      if (v == 0.f || (av > 1e-8f && av < 1e4f)) sane++;
    }
    ws[1700] = (sane >= 64) ? 1.f : 0.f;
  }
}

// Pre-swizzle weights into MFMA B-fragment order (bf16), into ws+8192 bytes.
#define FRAG_OLD 280576
#define FRAG_TOT 305152
template <bool BF16>
__global__ void prep_frags(const void* __restrict__ patch_w,
                           const void* __restrict__ Wq, const void* __restrict__ Wk,
                           const void* __restrict__ Wv, const void* __restrict__ Wg,
                           const void* __restrict__ Wo, const void* __restrict__ w1,
                           const void* __restrict__ w2,
                           const float* __restrict__ tab,
                           unsigned short* __restrict__ frag) {
  if ((tab[1700] > 0.5f) != BF16) return;
  int g = blockIdx.x * 256 + threadIdx.x;
  if (g >= FRAG_TOT) return;
  float v;
  if (g < 12288) {  // patch_w: K=192 (kt6), N=64 (nt4)
    int nt = g / 3072, r = g % 3072, kt = r / 512, r2 = r % 512, la = r2 >> 3, j = r2 & 7;
    int n = nt * 16 + (la & 15), k = kt * 32 + (la >> 4) * 8 + j;
    v = ld<BF16>(patch_w, k * 64 + n);
  } else if (g < FRAG_OLD) {
    int gg = g - 12288, l = gg / 33536, o = gg % 33536;
    if (o < 8192) {  // Wq / Wk
      const void* W = (o < 4096) ? Wq : Wk;
      int e = o & 4095;
      int nt = e / 1024, r = e % 1024, kt = r / 512, r2 = r % 512, la = r2 >> 3, j = r2 & 7;
      int n = nt * 16 + (la & 15), k = kt * 32 + (la >> 4) * 8 + j;
      v = ld<BF16>(W, l * 4096 + k * 64 + n);
    } else if (o < 24576) {  // Wv / Wg
      const void* W = (o < 16384) ? Wv : Wg;
      int e = (o - 8192) & 8191;
      int nt = e / 1024, r = e % 1024, kt = r / 512, r2 = r % 512, la = r2 >> 3, j = r2 & 7;
      int n = nt * 16 + (la & 15), k = kt * 32 + (la >> 4) * 8 + j;
      v = ld<BF16>(W, l * 8192 + k * 128 + n);
    } else if (o < 32768) {  // Wo
      int e = o - 24576;
      int nt = e / 2048, r = e % 2048, kt = r / 512, r2 = r % 512, la = r2 >> 3, j = r2 & 7;
      int n = nt * 16 + (la & 15), k = kt * 32 + (la >> 4) * 8 + j;
      v = ld<BF16>(Wo, l * 8192 + k * 64 + n);
    } else {  // legacy w1T (unused)
      int e = o - 32768, eo = e / 64, d = e % 64;
      v = ld<BF16>(w1, l * 768 + d * 12 + eo);
    }
  } else {  // w1 / w2 B-frags
    int gg = g - FRAG_OLD, l = gg / 3072, o = gg % 3072;
    if (o < 1024) {  // w1 B-frag: n=e (pad>=12), k=d, kt 0..1
      int kt = o >> 9, r = o & 511, la = r >> 3, j = r & 7;
      int n = la & 15, k = kt * 32 + (la >> 4) * 8 + j;
      v = (n < 12) ? ld<BF16>(w1, l * 768 + k * 12 + n) : 0.f;
    } else {  // w2 B-frag: n=d (nt 0..3), k=e (pad>=12), K=32
      int e2 = o - 1024;
      int nt = e2 >> 9, r = e2 & 511, la = r >> 3, j = r & 7;
      int n = nt * 16 + (la & 15), k = (la >> 4) * 8 + j;
      v = (k < 12) ? ld<BF16>(w2, (l * 12 + k) * 64 + n) : 0.f;
    }
  }
  __hip_bfloat16 h = __float2bfloat16(v);
  unsigned short us;
  __builtin_memcpy(&us, &h, 2);
  frag[g] = us;
}

// LDS float offsets
#define O_DM   0      // 1156 (dmask * 0.25 folded)
#define O_SIN  1156   // 272
#define O_COS  1428   // 272
#define O_ST   1700   // 512
#define O_H    2212   // 2244: H fp32 34x66
#define O_XNF  4456   // 1536: XN A-frags (ln1 / ln2)
#define O_FF   5992   // 408
#define O_R    6400   // 4624: Q 34x68 + K 34x68 / alias O fp32 34x130
#define O_SCA  11024  // 3072: patch A-frags / SC fp32 2x4x17x20 (2720) / OA frags
#define O_VG   14096  // 4872: VT bf16 2x128x20 (2560 f) + G bf16 34x136 (2312 f)
#define SM_TOT 18968

template <bool BF16>
__global__ void __launch_bounds__(512)
vit_fused(const void* __restrict__ x, const void* __restrict__ patch_b,
          const void* __restrict__ cls, const void* __restrict__ pos,
          const void* __restrict__ ln1s, const void* __restrict__ ln1b,
          const void* __restrict__ b1, const void* __restrict__ b2,
          const void* __restrict__ ln2s, const void* __restrict__ ln2b,
          const void* __restrict__ lnfs, const void* __restrict__ lnfb,
          const void* __restrict__ neckw, const void* __restrict__ neckb,
          const void* __restrict__ headw, const void* __restrict__ headb,
          const float* __restrict__ tab, const unsigned short* __restrict__ FR,
          void* __restrict__ out) {
  if ((tab[1700] > 0.5f) != BF16) return;

  const int tid = threadIdx.x;
  const int lane = tid & 63, w = tid >> 6;  // w in 0..7
  const int lq = lane >> 4, ln = lane & 15;
  const int img0 = 2 * blockIdx.x;

  __shared__ __align__(16) float sm[SM_TOT];
  float* sDM  = sm + O_DM;
  float* sSin = sm + O_SIN;
  float* sCos = sm + O_COS;
  float* sST  = sm + O_ST;
  float* sH   = sm + O_H;
  float* sFF  = sm + O_FF;
  float* sQ   = sm + O_R;          // 34x68
  float* sK   = sm + O_R + 2312;   // 34x68
  float* sO   = sm + O_R;          // alias, 34x130
  float* sSC  = sm + O_SCA;        // 2 x 4 x 17 x 20 (pitch-20 rows)
  unsigned short* sVbT = (unsigned short*)(sm + O_VG);          // 2 x 128 x 20 (c-major, t inner)
  unsigned short* sGb  = (unsigned short*)(sm + O_VG) + 5120;   // 34x136
  const bf16x8* FRB = (const bf16x8*)FR;

  // ---- stage tables + patch A-frags + cls rows ----
  for (int i = tid; i < 1156; i += 512) sDM[i] = tab[544 + i] * 0.25f;  // K-scale folded
  for (int i = tid; i < 272; i += 512) { sSin[i] = tab[i]; sCos[i] = tab[272 + i]; }
  for (int s = tid; s < 768; s += 512) {  // patch A-frags into O_SCA
    int mt = s / 384, r = s % 384, kt = r / 64, la = r % 64;
    int p = la & 15, q = la >> 4;
    int kb = kt * 32 + q * 8;
    int c = kb >> 6, rem = kb & 63, a = rem >> 3;
    int pi = p >> 2, pj = p & 3;
    int src = (img0 + mt) * 3072 + c * 1024 + (pi * 8 + a) * 32 + pj * 8;
    float v[8];
#pragma unroll
    for (int t2 = 0; t2 < 8; t2 += 2) {
      float2 pv = ld2<BF16>(x, src + t2);
      v[t2] = pv.x; v[t2 + 1] = pv.y;
    }
    i32x4 pk;
    pk.x = pack_bf2(v[0], v[1]); pk.y = pack_bf2(v[2], v[3]);
    pk.z = pack_bf2(v[4], v[5]); pk.w = pack_bf2(v[6], v[7]);
    ((i32x4*)(sm + O_SCA))[s] = pk;
  }
  if (tid < 128) {  // cls token rows
    int img = tid >> 6, n = tid & 63;
    sH[(img * 17) * 66 + n] = ld<BF16>(cls, n) + ld<BF16>(pos, n);
  }
  __syncthreads();

  // ---- patch embed MFMA: 8 jobs = 2mt x 4nt, one per wave ----
  {
    int mt = w >> 2, nt = w & 3;
    f32x4 acc = {0.f, 0.f, 0.f, 0.f};
    const bf16x8* paf = (const bf16x8*)(sm + O_SCA);
#pragma unroll
    for (int kt = 0; kt < 6; ++kt)
      acc = MFMA(paf[(mt * 6 + kt) * 64 + lane], FRB[(nt * 6 + kt) * 64 + lane], acc, 0, 0, 0);
    int n = nt * 16 + ln;
    float pb = ld<BF16>(patch_b, n);
#pragma unroll
    for (int i = 0; i < 4; ++i) {
      int t = 1 + lq * 4 + i;
      sH[(mt * 17 + t) * 66 + n] = acc[i] + pb + ld<BF16>(pos, t * 64 + n);
    }
  }
  __syncthreads();

  for (int l = 0; l < NLAY; ++l) {
    const int LB = 1536 + l * 4192;  // layer base, bf16x8 slots

    // ---- ln1 stats: 8 lanes per row + shuffle reduce ----
    if (tid < 272) {
      int m = tid >> 3, sub = tid & 7;
      const float2* hp = (const float2*)(sH + m * 66 + sub * 8);
      float s1 = 0.f, s2 = 0.f;
#pragma unroll
      for (int i = 0; i < 4; ++i) {
        float2 v = hp[i];
        s1 += v.x; s2 += v.x * v.x;
        s1 += v.y; s2 += v.y * v.y;
      }
      s1 += __shfl_xor(s1, 1); s2 += __shfl_xor(s2, 1);
      s1 += __shfl_xor(s1, 2); s2 += __shfl_xor(s2, 2);
      s1 += __shfl_xor(s1, 4); s2 += __shfl_xor(s2, 4);
      if (sub == 0) {
        float mu = s1 * (1.f / 64.f);
        float var = s2 * (1.f / 64.f) - mu * mu;
        sST[m] = mu;
        sST[34 + m] = rsqrtf(var + 1e-5f);
      }
    }
    __syncthreads();

    // ---- ln1 -> XN A-frags (bf16) ----
    if (tid < 384) {
      int s = tid;
      int mt = s >> 7, kt = (s >> 6) & 1, la = s & 63;
      int m = mt * 16 + (la & 15), q = la >> 4;
      int kb = kt * 32 + q * 8;
      i32x4 pk = {0, 0, 0, 0};
      if (m < 34) {
        float mu = sST[m], rr = sST[34 + m];
        float sv[8], bv[8];
        ld8v<BF16>(ln1s, l * 64 + kb, sv);
        ld8v<BF16>(ln1b, l * 64 + kb, bv);
        const float2* hp = (const float2*)(sH + m * 66 + kb);
        float vv[8];
#pragma unroll
        for (int t2 = 0; t2 < 4; ++t2) {
          float2 h = hp[t2];
          vv[2 * t2]     = (h.x - mu) * rr * sv[2 * t2] + bv[2 * t2];
          vv[2 * t2 + 1] = (h.y - mu) * rr * sv[2 * t2 + 1] + bv[2 * t2 + 1];
        }
        pk.x = pack_bf2(vv[0], vv[1]); pk.y = pack_bf2(vv[2], vv[3]);
        pk.z = pack_bf2(vv[4], vv[5]); pk.w = pack_bf2(vv[6], vv[7]);
      }
      ((i32x4*)(sm + O_XNF))[s] = pk;
    }
    __syncthreads();

    // ---- QKVG MFMA: 3 phases (QK / V / G) x 3 mt, specialized stores ----
    {
      const bf16x8* xnf = (const bf16x8*)(sm + O_XNF);
      // phase QK: waves 0-3 -> Q, waves 4-7 -> K
      {
        const bf16x8* wf = FRB + LB + ((w < 4) ? 0 : 512);
        float* dst = (w < 4) ? sQ : sK;
        int ntl = w & 3;
        int n = ntl * 16 + ln;
#pragma unroll
        for (int mt = 0; mt < 3; ++mt) {
          f32x4 acc = {0.f, 0.f, 0.f, 0.f};
          acc = MFMA(xnf[(mt * 2) * 64 + lane], wf[(ntl * 2) * 64 + lane], acc, 0, 0, 0);
          acc = MFMA(xnf[(mt * 2 + 1) * 64 + lane], wf[(ntl * 2 + 1) * 64 + lane], acc, 0, 0, 0);
          if (mt < 2) {
            float* p = dst + (mt * 16 + lq * 4) * 68 + n;
            p[0] = acc[0]; p[68] = acc[1]; p[136] = acc[2]; p[204] = acc[3];
          } else if (lq == 0) {
            float* p = dst + 32 * 68 + n;
            p[0] = acc[0]; p[68] = acc[1];
          }
        }
      }
      // phase V: transposed bf16 store, n = w*16+ln in 0..127
      {
        const bf16x8* wf = FRB + LB + 1024;
        int n = w * 16 + ln;
#pragma unroll
        for (int mt = 0; mt < 3; ++mt) {
          f32x4 acc = {0.f, 0.f, 0.f, 0.f};
          acc = MFMA(xnf[(mt * 2) * 64 + lane], wf[(w * 2) * 64 + lane], acc, 0, 0, 0);
          acc = MFMA(xnf[(mt * 2 + 1) * 64 + lane], wf[(w * 2 + 1) * 64 + lane], acc, 0, 0, 0);
          if (mt == 0) {  // img0, t = lq*4..+3: one b64 store
            uint2 uv;
            uv.x = pack_bf2(acc[0], acc[1]);
            uv.y = pack_bf2(acc[2], acc[3]);
            *(uint2*)(sVbT + n * 20 + lq * 4) = uv;
          } else if (mt == 1) {  // straddles image boundary
#pragma unroll
            for (int i = 0; i < 4; ++i) {
              int m = 16 + lq * 4 + i;
              int img = (m >= 17), t = m - img * 17;
              sVbT[img * 2560 + n * 20 + t] = cvt_bf(acc[i]);
            }
          } else if (lq == 0) {  // m=32,33 -> img1 t=15,16
            sVbT[2560 + n * 20 + 15] = cvt_bf(acc[0]);
            sVbT[2560 + n * 20 + 16] = cvt_bf(acc[1]);
          }
        }
      }
      // phase G: row-major bf16, n = w*16+ln in 0..127
      {
        const bf16x8* wf = FRB + LB + 2048;
        int n = w * 16 + ln;
#pragma unroll
        for (int mt = 0; mt < 3; ++mt) {
          f32x4 acc = {0.f, 0.f, 0.f, 0.f};
          acc = MFMA(xnf[(mt * 2) * 64 + lane], wf[(w * 2) * 64 + lane], acc, 0, 0, 0);
          acc = MFMA(xnf[(mt * 2 + 1) * 64 + lane], wf[(w * 2 + 1) * 64 + lane], acc, 0, 0, 0);
          if (mt < 2) {
            unsigned short* p = sGb + (mt * 16 + lq * 4) * 136 + n;
            p[0] = cvt_bf(acc[0]); p[136] = cvt_bf(acc[1]);
            p[272] = cvt_bf(acc[2]); p[408] = cvt_bf(acc[3]);
          } else if (lq == 0) {
            sGb[32 * 136 + n] = cvt_bf(acc[0]);
            sGb[33 * 136 + n] = cvt_bf(acc[1]);
          }
        }
      }
    }
    __syncthreads();

    // ---- scores via MFMA 32x32x16: 8 jobs (img, head), rotary fused in frag build ----
    {
      int img = w >> 2, hh = w & 3;
      int cl = lane & 31, kh = lane >> 5;
      int tt = (cl < 17) ? cl : 16;  // clamp garbage rows (discarded at store)
      int rb = (img * 17 + tt) * 68 + hh * 16 + kh * 8;
      int sb = tt * 16 + kh * 8;
      float4 s0 = *(const float4*)(sSin + sb), s1 = *(const float4*)(sSin + sb + 4);
      float4 c0 = *(const float4*)(sCos + sb), c1 = *(const float4*)(sCos + sb + 4);
      float4 qa = *(const float4*)(sQ + rb), qb = *(const float4*)(sQ + rb + 4);
      i32x4 ap;
      ap.x = pack_bf2(qa.x * c0.x - qa.y * s0.x, qa.y * c0.y + qa.x * s0.y);
      ap.y = pack_bf2(qa.z * c0.z - qa.w * s0.z, qa.w * c0.w + qa.z * s0.w);
      ap.z = pack_bf2(qb.x * c1.x - qb.y * s1.x, qb.y * c1.y + qb.x * s1.y);
      ap.w = pack_bf2(qb.z * c1.z - qb.w * s1.z, qb.w * c1.w + qb.z * s1.w);
      float4 ka = *(const float4*)(sK + rb), kb = *(const float4*)(sK + rb + 4);
      i32x4 bp;
      bp.x = pack_bf2(ka.x * c0.x - ka.y * s0.x, ka.y * c0.y + ka.x * s0.y);
      bp.y = pack_bf2(ka.z * c0.z - ka.w * s0.z, ka.w * c0.w + ka.z * s0.w);
      bp.z = pack_bf2(kb.x * c1.x - kb.y * s1.x, kb.y * c1.y + kb.x * s1.y);
      bp.w = pack_bf2(kb.z * c1.z - kb.w * s1.z, kb.w * c1.w + kb.z * s1.w);
      f32x16 acc = {0.f, 0.f, 0.f, 0.f, 0.f, 0.f, 0.f, 0.f,
                    0.f, 0.f, 0.f, 0.f, 0.f, 0.f, 0.f, 0.f};
      acc = MFMA32(as_bf(ap), as_bf(bp), acc, 0, 0, 0);
      if (cl < 17) {  // valid u column; dmask (incl 0.25) zeroes u>t
        int scb = img * 1360 + hh * 340;
        const float* dmb = sDM + hh * 289;
#pragma unroll
        for (int r = 0; r < 16; ++r) {
          int t = (r & 3) + 8 * (r >> 2) + 4 * kh;
          if (t < 17) sSC[scb + t * 20 + cl] = acc[r] * dmb[t * 17 + cl];
        }
      }
    }
    __syncthreads();

    // ---- denominators ----
    if (tid < 136) {
      const float* base = sSC + tid * 20;
      float s = 0.f;
      for (int u = 0; u < 17; ++u) s += base[u];
      float den = fabsf(s);
      if (den < 1.f) den = 1.f;
      sST[68 + tid] = 1.f / den;
    }
    __syncthreads();

    // ---- AV via MFMA 32x32x16: 8 jobs (img, head), one per wave ----
    {
      int img = w >> 2, hh = w & 3;
      int cl = lane & 31, kh = lane >> 5;   // cl: A-row t / B-col c; kh: k-half
      int tt = (cl < 17) ? cl : 16;         // clamp invalid rows (discarded at store)
      const float* scb = sSC + img * 1360 + hh * 340;
      float den = sST[68 + img * 68 + hh * 17 + tt];
      const float4* a4 = (const float4*)(scb + tt * 20 + kh * 8);
      float4 av0 = a4[0], av1 = a4[1];
      i32x4 ap;
      ap.x = pack_bf2(av0.x * den, av0.y * den);
      ap.y = pack_bf2(av0.z * den, av0.w * den);
      ap.z = pack_bf2(av1.x * den, av1.y * den);
      ap.w = pack_bf2(av1.z * den, av1.w * den);
      const unsigned short* vcol = sVbT + img * 2560 + (hh * 32 + cl) * 20 + kh * 8;
      const uint2* vq = (const uint2*)vcol;
      uint2 v0 = vq[0], v1 = vq[1];
      i32x4 bp; bp.x = (int)v0.x; bp.y = (int)v0.y; bp.z = (int)v1.x; bp.w = (int)v1.y;
      f32x16 acc = {0.f, 0.f, 0.f, 0.f, 0.f, 0.f, 0.f, 0.f,
                    0.f, 0.f, 0.f, 0.f, 0.f, 0.f, 0.f, 0.f};
      acc = MFMA32(as_bf(ap), as_bf(bp), acc, 0, 0, 0);
      i32x4 a1 = {0, 0, 0, 0}, b1v = {0, 0, 0, 0};
      if (kh == 0) {  // u = 16 tail
        float s16 = scb[tt * 20 + 16] * den;
        a1.x = (int)(unsigned)cvt_bf(s16);
        b1v.x = (int)(unsigned)sVbT[img * 2560 + (hh * 32 + cl) * 20 + 16];
      }
      acc = MFMA32(as_bf(a1), as_bf(b1v), acc, 0, 0, 0);
      int cg = hh * 32 + cl;
#pragma unroll
      for (int r = 0; r < 16; ++r) {
        int t = (r & 3) + 8 * (r >> 2) + 4 * kh;
        if (t < 17) sO[(img * 17 + t) * 130 + cg] = acc[r];
      }
    }
    __syncthreads();

    // ---- group norm stats: 2 lanes per row ----
    if (tid < 272) {
      int row = tid >> 1, sub = tid & 1;  // row = img*68 + hh*17 + t
      int img = row / 68, hr = row % 68, hh = hr / 17, t = hr % 17;
      int m = img * 17 + t;
      const float2* op = (const float2*)(sO + m * 130 + hh * 32 + sub * 16);
      float s1 = 0.f, s2 = 0.f;
#pragma unroll
      for (int i = 0; i < 8; ++i) {
        float2 v = op[i];
        s1 += v.x; s2 += v.x * v.x;
        s1 += v.y; s2 += v.y * v.y;
      }
      s1 += __shfl_xor(s1, 1); s2 += __shfl_xor(s2, 1);
      if (sub == 0) {
        float mu = s1 * (1.f / 32.f);
        float var = s2 * (1.f / 32.f) - mu * mu;
        sST[204 + row] = mu;
        sST[340 + row] = rsqrtf(var + 1e-5f);
      }
    }
    __syncthreads();

    // ---- groupnorm + silu gate -> OA frags ----
    for (int s = tid; s < 768; s += 512) {
      int mt = s >> 8, kt = (s >> 6) & 3, la = s & 63;
      int q = la >> 4, m = mt * 16 + (la & 15);
      int cb = kt * 32 + q * 8;
      i32x4 pk = {0, 0, 0, 0};
      if (m < 34) {
        int img = (m >= 17), t = m - img * 17;
        int sti = img * 68 + kt * 17 + t;
        float mu = sST[204 + sti], rr = sST[340 + sti];
        const float2* op = (const float2*)(sO + m * 130 + cb);
        i32x4 gu = *(const i32x4*)(sGb + m * 136 + cb);
        float vv[8];
#pragma unroll
        for (int q2 = 0; q2 < 4; ++q2) {
          float2 ov = op[q2];
          unsigned gw = (q2 == 0) ? (unsigned)gu.x : (q2 == 1) ? (unsigned)gu.y
                       : (q2 == 2) ? (unsigned)gu.z : (unsigned)gu.w;
          float2 gv = unpk(gw);
          float on0 = (ov.x - mu) * rr;
          float on1 = (ov.y - mu) * rr;
          vv[2 * q2]     = on0 * (gv.x / (1.f + __expf(-gv.x)));
          vv[2 * q2 + 1] = on1 * (gv.y / (1.f + __expf(-gv.y)));
        }
        pk.x = pack_bf2(vv[0], vv[1]); pk.y = pack_bf2(vv[2], vv[3]);
        pk.z = pack_bf2(vv[4], vv[5]); pk.w = pack_bf2(vv[6], vv[7]);
      }
      ((i32x4*)(sm + O_SCA))[s] = pk;
    }
    __syncthreads();

    // ---- Wo MFMA: 12 jobs / 8 waves; += residual ----
    {
      const bf16x8* oaf = (const bf16x8*)(sm + O_SCA);
      const bf16x8* wof = FRB + LB + 3072;
      for (int j = w; j < 12; j += 8) {
        int mt = j >> 2, nt = j & 3;
        f32x4 acc = {0.f, 0.f, 0.f, 0.f};
#pragma unroll
        for (int kt = 0; kt < 4; ++kt)
          acc = MFMA(oaf[(mt * 4 + kt) * 64 + lane], wof[(nt * 4 + kt) * 64 + lane], acc, 0, 0, 0);
        int n = nt * 16 + ln;
#pragma unroll
        for (int i = 0; i < 4; ++i) {
          int m = mt * 16 + lq * 4 + i;
          if (m < 34) sH[m * 66 + n] += acc[i];
        }
      }
    }
    __syncthreads();

    // ---- ln2 stats ----
    if (tid < 272) {
      int m = tid >> 3, sub = tid & 7;
      const float2* hp = (const float2*)(sH + m * 66 + sub * 8);
      float s1 = 0.f, s2 = 0.f;
#pragma unroll
      for (int i = 0; i < 4; ++i) {
        float2 v = hp[i];
        s1 += v.x; s2 += v.x * v.x;
        s1 += v.y; s2 += v.y * v.y;
      }
      s1 += __shfl_xor(s1, 1); s2 += __shfl_xor(s2, 1);
      s1 += __shfl_xor(s1, 2); s2 += __shfl_xor(s2, 2);
      s1 += __shfl_xor(s1, 4); s2 += __shfl_xor(s2, 4);
      if (sub == 0) {
        float mu = s1 * (1.f / 64.f);
        float var = s2 * (1.f / 64.f) - mu * mu;
        sST[m] = mu;
        sST[34 + m] = rsqrtf(var + 1e-5f);
      }
    }
    __syncthreads();

    // ---- ln2 -> XN2 A-frags (bf16) ----
    if (tid < 384) {
      int s = tid;
      int mt = s >> 7, kt = (s >> 6) & 1, la = s & 63;
      int m = mt * 16 + (la & 15), q = la >> 4;
      int kb = kt * 32 + q * 8;
      i32x4 pk = {0, 0, 0, 0};
      if (m < 34) {
        float mu = sST[m], rr = sST[34 + m];
        float sv[8], bv[8];
        ld8v<BF16>(ln2s, l * 64 + kb, sv);
        ld8v<BF16>(ln2b, l * 64 + kb, bv);
        const float2* hp = (const float2*)(sH + m * 66 + kb);
        float vv[8];
#pragma unroll
        for (int t2 = 0; t2 < 4; ++t2) {
          float2 h = hp[t2];
          vv[2 * t2]     = (h.x - mu) * rr * sv[2 * t2] + bv[2 * t2];
          vv[2 * t2 + 1] = (h.y - mu) * rr * sv[2 * t2 + 1] + bv[2 * t2 + 1];
        }
        pk.x = pack_bf2(vv[0], vv[1]); pk.y = pack_bf2(vv[2], vv[3]);
        pk.z = pack_bf2(vv[4], vv[5]); pk.w = pack_bf2(vv[6], vv[7]);
      }
      ((i32x4*)(sm + O_XNF))[s] = pk;
    }
    __syncthreads();

    // ---- FFN1 via MFMA: 3 jobs (mt), N=12 in one 16-tile, K=64; gelu at store ----
    if (w < 3) {
      const bf16x8* xnf = (const bf16x8*)(sm + O_XNF);
      const bf16x8* w1f = FRB + 35072 + l * 384;
      int mt = w;
      f32x4 acc = {0.f, 0.f, 0.f, 0.f};
#pragma unroll
      for (int kt = 0; kt < 2; ++kt)
        acc = MFMA(xnf[(mt * 2 + kt) * 64 + lane], w1f[kt * 64 + lane], acc, 0, 0, 0);
      if (ln < 12) {
        float b = ld<BF16>(b1, l * 12 + ln);
#pragma unroll
        for (int i = 0; i < 4; ++i) {
          int m = mt * 16 + lq * 4 + i;
          if (m < 34) {
            float a = acc[i] + b;
            float inner = 0.7978845608028654f * (a + 0.044715f * a * a * a);
            float e = __expf(2.f * inner);
            float th = 1.f - 2.f / (e + 1.f);
            sFF[m * 12 + ln] = 0.5f * a * (1.f + th);
          }
        }
      }
    }
    __syncthreads();

    // ---- FFN2 via MFMA: 12 jobs (mt3 x nt4), K=32 (e padded); bias+residual at store ----
    {
      const bf16x8* w2f = FRB + 35072 + l * 384 + 128;
      for (int j = w; j < 12; j += 8) {
        int mt = j >> 2, nt = j & 3;
        i32x4 ap = {0, 0, 0, 0};
        int ma = mt * 16 + ln;
        if (ma < 34) {
          const float* fp = sFF + ma * 12;
          if (lq == 0) {
            ap.x = pack_bf2(fp[0], fp[1]); ap.y = pack_bf2(fp[2], fp[3]);
            ap.z = pack_bf2(fp[4], fp[5]); ap.w = pack_bf2(fp[6], fp[7]);
          } else if (lq == 1) {
            ap.x = pack_bf2(fp[8], fp[9]); ap.y = pack_bf2(fp[10], fp[11]);
          }
        }
        f32x4 acc = {0.f, 0.f, 0.f, 0.f};
        acc = MFMA(as_bf(ap), w2f[nt * 64 + lane], acc, 0, 0, 0);
        int n = nt * 16 + ln;
        float b = ld<BF16>(b2, l * 64 + n);
#pragma unroll
        for (int i = 0; i < 4; ++i) {
          int m = mt * 16 + lq * 4 + i;
          if (m < 34) sH[m * 66 + n] += acc[i] + b;
        }
      }
    }
    __syncthreads();
  }

  // ---- final: lnf (last token each image), neck, head ----
  if (tid < 2) {
    int m = tid * 17 + 16;
    float s1 = 0.f, s2 = 0.f;
    for (int d = 0; d < 64; ++d) {
      float v = sH[m * 66 + d];
      s1 += v; s2 += v * v;
    }
    float mu = s1 * (1.f / 64.f);
    float var = s2 * (1.f / 64.f) - mu * mu;
    sST[tid] = mu;
    sST[2 + tid] = rsqrtf(var + 1e-5f);
  }
  __syncthreads();
  if (tid < 32) {
    int img = tid >> 4, jn = tid & 15;
    int m = img * 17 + 16;
    float mu = sST[img], rr = sST[2 + img];
    float acc = ld<BF16>(neckb, jn);
    for (int d = 0; d < 64; ++d) {
      float yn = (sH[m * 66 + d] - mu) * rr * ld<BF16>(lnfs, d) + ld<BF16>(lnfb, d);
      acc += yn * ld<BF16>(neckw, d * 16 + jn);
    }
    sST[8 + img * 16 + jn] = acc;
  }
  __syncthreads();
  if (tid < 20) {
    int img = tid / 10, o = tid % 10;
    float acc = ld<BF16>(headb, o);
#pragma unroll
    for (int e = 0; e < 16; ++e) acc += sST[8 + img * 16 + e] * ld<BF16>(headw, e * 10 + o);
    if (BF16) {
      ((__hip_bfloat16*)out)[(img0 + img) * 10 + o] = __float2bfloat16(acc);
    } else {
      ((float*)out)[(img0 + img) * 10 + o] = acc;
    }
  }
}

extern "C" void kernel_launch(void* const* d_in, const int* in_sizes, int n_in,
                              void* d_out, int out_size, void* d_ws, size_t ws_size,
                              hipStream_t stream) {
  float* tab = (float*)d_ws;
  unsigned short* frag = (unsigned short*)((char*)d_ws + 8192);

  setup_tables<<<dim3(1), dim3(256), 0, stream>>>(tab, d_in[0]);

  const int prepBlocks = (FRAG_TOT + 255) / 256;
  prep_frags<false><<<dim3(prepBlocks), dim3(256), 0, stream>>>(
      d_in[1], d_in[5], d_in[6], d_in[7], d_in[8], d_in[9], d_in[12], d_in[14], tab, frag);
  prep_frags<true><<<dim3(prepBlocks), dim3(256), 0, stream>>>(
      d_in[1], d_in[5], d_in[6], d_in[7], d_in[8], d_in[9], d_in[12], d_in[14], tab, frag);

  const int B = in_sizes[0] / 3072;
  const int grid = B / 2;

  vit_fused<false><<<dim3(grid), dim3(512), 0, stream>>>(
      d_in[0], d_in[2], d_in[3], d_in[4], d_in[10], d_in[11], d_in[13],
      d_in[15], d_in[16], d_in[17], d_in[18], d_in[19], d_in[20], d_in[21],
      d_in[22], d_in[23], tab, frag, d_out);
  vit_fused<true><<<dim3(grid), dim3(512), 0, stream>>>(
      d_in[0], d_in[2], d_in[3], d_in[4], d_in[10], d_in[11], d_in[13],
      d_in[15], d_in[16], d_in[17], d_in[18], d_in[19], d_in[20], d_in[21],
      d_in[22], d_in[23], tab, frag, d_out);
}

// Round 6
// 827.609 us; speedup vs baseline: 1.4831x; 1.4831x over previous
//
#include <hip/hip_runtime.h>
#include <hip/hip_bf16.h>

#define NLAY 8
#define MFMA __builtin_amdgcn_mfma_f32_16x16x32_bf16
#define MFMA32 __builtin_amdgcn_mfma_f32_32x32x16_bf16

typedef __attribute__((ext_vector_type(8))) short bf16x8;
typedef __attribute__((ext_vector_type(4))) float f32x4;
typedef __attribute__((ext_vector_type(16))) float f32x16;
typedef __attribute__((ext_vector_type(4))) int i32x4;

template <bool BF16>
__device__ __forceinline__ float ld(const void* p, int i) {
  if (BF16) {
    unsigned short u = ((const unsigned short*)p)[i];
    return __uint_as_float(((unsigned)u) << 16);
  }
  return ((const float*)p)[i];
}

template <bool BF16>
__device__ __forceinline__ float2 ld2(const void* p, int i) {  // i even
  float2 r;
  if (BF16) {
    unsigned u = ((const unsigned*)p)[i >> 1];
    r.x = __uint_as_float(u << 16);
    r.y = __uint_as_float(u & 0xffff0000u);
  } else {
    r = ((const float2*)p)[i >> 1];
  }
  return r;
}

__device__ __forceinline__ float bfu(unsigned short u) {
  return __uint_as_float(((unsigned)u) << 16);
}

__device__ __forceinline__ unsigned pack_bf2(float a, float b) {
  __hip_bfloat16 ha = __float2bfloat16(a), hb = __float2bfloat16(b);
  unsigned short ua, ub;
  __builtin_memcpy(&ua, &ha, 2);
  __builtin_memcpy(&ub, &hb, 2);
  return ((unsigned)ub << 16) | (unsigned)ua;
}

__device__ __forceinline__ unsigned short cvt_bf(float a) {
  __hip_bfloat16 h = __float2bfloat16(a);
  unsigned short us;
  __builtin_memcpy(&us, &h, 2);
  return us;
}

__device__ __forceinline__ float2 unpk(unsigned u) {
  float2 r;
  r.x = __uint_as_float(u << 16);
  r.y = __uint_as_float(u & 0xffff0000u);
  return r;
}

__device__ __forceinline__ bf16x8 as_bf(i32x4 v) {
  bf16x8 r;
  __builtin_memcpy(&r, &v, 16);
  return r;
}

// ws[0..271]=sin, ws[272..543]=cos, ws[544..1699]=dmask, ws[1700]=dtype flag
__global__ void setup_tables(float* __restrict__ ws, const void* __restrict__ x) {
  int tid = threadIdx.x;
  for (int idx = tid; idx < 272; idx += 256) {
    int t = idx >> 4, j = idx & 15;
    float a = powf(10000.f, -(float)(j >> 1) / 7.f);
    float arg = (float)t * a;
    ws[idx] = sinf(arg);
    ws[272 + idx] = cosf(arg);
  }
  for (int row = tid; row < 68; row += 256) {
    int hh = row / 17, t = row % 17;
    float gamma = 1.f - exp2f(-5.f - 4.f * (float)hh / 3.f);
    float sum = 0.f;
    for (int u = 0; u <= t; ++u) sum += powf(gamma, (float)(t - u));
    float rn = rsqrtf(sum);
    for (int u = 0; u < 17; ++u)
      ws[544 + row * 17 + u] = (u <= t) ? powf(gamma, (float)(t - u)) * rn : 0.f;
  }
  if (tid == 0) {
    const unsigned short* u16 = (const unsigned short*)x;
    int sane = 0;
    for (int i = 0; i < 128; ++i) {
      float v = __uint_as_float(((unsigned)u16[2 * i]) << 16);
      float av = fabsf(v);
      if (v == 0.f || (av > 1e-8f && av < 1e4f)) sane++;
    }
    ws[1700] = (sane >= 64) ? 1.f : 0.f;
  }
}

// Pre-swizzle weights into MFMA B-fragment order (bf16), into ws+8192 bytes.
#define FRAG_OLD 280576
#define FRAG_TOT 305152
template <bool BF16>
__global__ void prep_frags(const void* __restrict__ patch_w,
                           const void* __restrict__ Wq, const void* __restrict__ Wk,
                           const void* __restrict__ Wv, const void* __restrict__ Wg,
                           const void* __restrict__ Wo, const void* __restrict__ w1,
                           const void* __restrict__ w2,
                           const float* __restrict__ tab,
                           unsigned short* __restrict__ frag) {
  if ((tab[1700] > 0.5f) != BF16) return;
  int g = blockIdx.x * 256 + threadIdx.x;
  if (g >= FRAG_TOT) return;
  float v;
  if (g < 12288) {  // patch_w: K=192 (kt6), N=64 (nt4)
    int nt = g / 3072, r = g % 3072, kt = r / 512, r2 = r % 512, la = r2 >> 3, j = r2 & 7;
    int n = nt * 16 + (la & 15), k = kt * 32 + (la >> 4) * 8 + j;
    v = ld<BF16>(patch_w, k * 64 + n);
  } else if (g < FRAG_OLD) {
    int gg = g - 12288, l = gg / 33536, o = gg % 33536;
    if (o < 8192) {  // Wq / Wk
      const void* W = (o < 4096) ? Wq : Wk;
      int e = o & 4095;
      int nt = e / 1024, r = e % 1024, kt = r / 512, r2 = r % 512, la = r2 >> 3, j = r2 & 7;
      int n = nt * 16 + (la & 15), k = kt * 32 + (la >> 4) * 8 + j;
      v = ld<BF16>(W, l * 4096 + k * 64 + n);
    } else if (o < 24576) {  // Wv / Wg
      const void* W = (o < 16384) ? Wv : Wg;
      int e = (o - 8192) & 8191;
      int nt = e / 1024, r = e % 1024, kt = r / 512, r2 = r % 512, la = r2 >> 3, j = r2 & 7;
      int n = nt * 16 + (la & 15), k = kt * 32 + (la >> 4) * 8 + j;
      v = ld<BF16>(W, l * 8192 + k * 128 + n);
    } else if (o < 32768) {  // Wo
      int e = o - 24576;
      int nt = e / 2048, r = e % 2048, kt = r / 512, r2 = r % 512, la = r2 >> 3, j = r2 & 7;
      int n = nt * 16 + (la & 15), k = kt * 32 + (la >> 4) * 8 + j;
      v = ld<BF16>(Wo, l * 8192 + k * 64 + n);
    } else {  // legacy w1T (unused)
      int e = o - 32768, eo = e / 64, d = e % 64;
      v = ld<BF16>(w1, l * 768 + d * 12 + eo);
    }
  } else {  // w1 / w2 B-frags
    int gg = g - FRAG_OLD, l = gg / 3072, o = gg % 3072;
    if (o < 1024) {  // w1 B-frag: n=e (pad>=12), k=d, kt 0..1
      int kt = o >> 9, r = o & 511, la = r >> 3, j = r & 7;
      int n = la & 15, k = kt * 32 + (la >> 4) * 8 + j;
      v = (n < 12) ? ld<BF16>(w1, l * 768 + k * 12 + n) : 0.f;
    } else {  // w2 B-frag: n=d (nt 0..3), k=e (pad>=12), K=32
      int e2 = o - 1024;
      int nt = e2 >> 9, r = e2 & 511, la = r >> 3, j = r & 7;
      int n = nt * 16 + (la & 15), k = (la >> 4) * 8 + j;
      v = (k < 12) ? ld<BF16>(w2, (l * 12 + k) * 64 + n) : 0.f;
    }
  }
  __hip_bfloat16 h = __float2bfloat16(v);
  unsigned short us;
  __builtin_memcpy(&us, &h, 2);
  frag[g] = us;
}

// LDS float offsets
#define O_DM   0      // 1156 (dmask * 0.25 folded)
#define O_SIN  1156   // 272
#define O_COS  1428   // 272
#define O_ST   1700   // 512
#define O_H    2212   // 2244: H fp32 34x66
#define O_XNF  4456   // 1536: XN A-frags (ln1 / ln2)
#define O_FF   5992   // 408
#define O_R    6400   // 4624: Q 34x68 + K 34x68 / alias O fp32 34x130
#define O_SCA  11024  // 3072: patch A-frags / SC fp32 2x4x17x20 (2720) / OA frags
#define O_VG   14096  // 4872: VT bf16 2x128x20 (2560 f) + G bf16 34x136 (2312 f)
#define SM_TOT 18968

template <bool BF16>
__global__ void __launch_bounds__(512, 4)
vit_fused(const void* __restrict__ x, const void* __restrict__ patch_b,
          const void* __restrict__ cls, const void* __restrict__ pos,
          const void* __restrict__ ln1s, const void* __restrict__ ln1b,
          const void* __restrict__ b1, const void* __restrict__ b2,
          const void* __restrict__ ln2s, const void* __restrict__ ln2b,
          const void* __restrict__ lnfs, const void* __restrict__ lnfb,
          const void* __restrict__ neckw, const void* __restrict__ neckb,
          const void* __restrict__ headw, const void* __restrict__ headb,
          const float* __restrict__ tab, const unsigned short* __restrict__ FR,
          void* __restrict__ out) {
  if ((tab[1700] > 0.5f) != BF16) return;

  const int tid = threadIdx.x;
  const int lane = tid & 63, w = tid >> 6;  // w in 0..7
  const int lq = lane >> 4, ln = lane & 15;
  const int img0 = 2 * blockIdx.x;

  __shared__ __align__(16) float sm[SM_TOT];
  float* sDM  = sm + O_DM;
  float* sSin = sm + O_SIN;
  float* sCos = sm + O_COS;
  float* sST  = sm + O_ST;
  float* sH   = sm + O_H;
  float* sFF  = sm + O_FF;
  float* sQ   = sm + O_R;          // 34x68
  float* sK   = sm + O_R + 2312;   // 34x68
  float* sO   = sm + O_R;          // alias, 34x130
  float* sSC  = sm + O_SCA;        // 2 x 4 x 17 x 20 (pitch-20 rows)
  unsigned short* sVbT = (unsigned short*)(sm + O_VG);          // 2 x 128 x 20 (c-major, t inner)
  unsigned short* sGb  = (unsigned short*)(sm + O_VG) + 5120;   // 34x136
  const bf16x8* FRB = (const bf16x8*)FR;

  // ---- stage tables + patch A-frags + cls rows ----
  for (int i = tid; i < 1156; i += 512) sDM[i] = tab[544 + i] * 0.25f;  // K-scale folded
  for (int i = tid; i < 272; i += 512) { sSin[i] = tab[i]; sCos[i] = tab[272 + i]; }
  for (int s = tid; s < 768; s += 512) {  // patch A-frags into O_SCA
    int mt = s / 384, r = s % 384, kt = r / 64, la = r % 64;
    int p = la & 15, q = la >> 4;
    int kb = kt * 32 + q * 8;
    int c = kb >> 6, rem = kb & 63, a = rem >> 3;
    int pi = p >> 2, pj = p & 3;
    int src = (img0 + mt) * 3072 + c * 1024 + (pi * 8 + a) * 32 + pj * 8;
    float v[8];
#pragma unroll
    for (int t2 = 0; t2 < 8; t2 += 2) {
      float2 pv = ld2<BF16>(x, src + t2);
      v[t2] = pv.x; v[t2 + 1] = pv.y;
    }
    i32x4 pk;
    pk.x = pack_bf2(v[0], v[1]); pk.y = pack_bf2(v[2], v[3]);
    pk.z = pack_bf2(v[4], v[5]); pk.w = pack_bf2(v[6], v[7]);
    ((i32x4*)(sm + O_SCA))[s] = pk;
  }
  if (tid < 128) {  // cls token rows
    int img = tid >> 6, n = tid & 63;
    sH[(img * 17) * 66 + n] = ld<BF16>(cls, n) + ld<BF16>(pos, n);
  }
  __syncthreads();

  // ---- patch embed MFMA: 8 jobs = 2mt x 4nt, one per wave ----
  {
    int mt = w >> 2, nt = w & 3;
    f32x4 acc = {0.f, 0.f, 0.f, 0.f};
    const bf16x8* paf = (const bf16x8*)(sm + O_SCA);
#pragma unroll
    for (int kt = 0; kt < 6; ++kt)
      acc = MFMA(paf[(mt * 6 + kt) * 64 + lane], FRB[(nt * 6 + kt) * 64 + lane], acc, 0, 0, 0);
    int n = nt * 16 + ln;
    float pb = ld<BF16>(patch_b, n);
#pragma unroll
    for (int i = 0; i < 4; ++i) {
      int t = 1 + lq * 4 + i;
      sH[(mt * 17 + t) * 66 + n] = acc[i] + pb + ld<BF16>(pos, t * 64 + n);
    }
  }
  __syncthreads();

  for (int l = 0; l < NLAY; ++l) {
    const int LB = 1536 + l * 4192;  // layer base, bf16x8 slots

    // ---- ln1 stats: 8 lanes per row + shuffle reduce ----
    if (tid < 272) {
      int m = tid >> 3, sub = tid & 7;
      const float2* hp = (const float2*)(sH + m * 66 + sub * 8);
      float s1 = 0.f, s2 = 0.f;
#pragma unroll
      for (int i = 0; i < 4; ++i) {
        float2 v = hp[i];
        s1 += v.x; s2 += v.x * v.x;
        s1 += v.y; s2 += v.y * v.y;
      }
      s1 += __shfl_xor(s1, 1); s2 += __shfl_xor(s2, 1);
      s1 += __shfl_xor(s1, 2); s2 += __shfl_xor(s2, 2);
      s1 += __shfl_xor(s1, 4); s2 += __shfl_xor(s2, 4);
      if (sub == 0) {
        float mu = s1 * (1.f / 64.f);
        float var = s2 * (1.f / 64.f) - mu * mu;
        sST[m] = mu;
        sST[34 + m] = rsqrtf(var + 1e-5f);
      }
    }
    __syncthreads();

    // ---- ln1 -> XN A-frags (bf16) ----
    if (tid < 384) {
      int s = tid;
      int mt = s >> 7, kt = (s >> 6) & 1, la = s & 63;
      int m = mt * 16 + (la & 15), q = la >> 4;
      int kb = kt * 32 + q * 8;
      i32x4 pk = {0, 0, 0, 0};
      if (m < 34) {
        float mu = sST[m], rr = sST[34 + m];
        float vv[8];
#pragma unroll
        for (int t2 = 0; t2 < 8; t2 += 2) {
          float2 sv = ld2<BF16>(ln1s, l * 64 + kb + t2);
          float2 bv = ld2<BF16>(ln1b, l * 64 + kb + t2);
          vv[t2]     = (sH[m * 66 + kb + t2] - mu) * rr * sv.x + bv.x;
          vv[t2 + 1] = (sH[m * 66 + kb + t2 + 1] - mu) * rr * sv.y + bv.y;
        }
        pk.x = pack_bf2(vv[0], vv[1]); pk.y = pack_bf2(vv[2], vv[3]);
        pk.z = pack_bf2(vv[4], vv[5]); pk.w = pack_bf2(vv[6], vv[7]);
      }
      ((i32x4*)(sm + O_XNF))[s] = pk;
    }
    __syncthreads();

    // ---- QKVG MFMA: 3 phases (QK / V / G) x 3 mt, specialized stores ----
    {
      const bf16x8* xnf = (const bf16x8*)(sm + O_XNF);
      // phase QK: waves 0-3 -> Q, waves 4-7 -> K
      {
        const bf16x8* wf = FRB + LB + ((w < 4) ? 0 : 512);
        float* dst = (w < 4) ? sQ : sK;
        int ntl = w & 3;
        int n = ntl * 16 + ln;
#pragma unroll
        for (int mt = 0; mt < 3; ++mt) {
          f32x4 acc = {0.f, 0.f, 0.f, 0.f};
          acc = MFMA(xnf[(mt * 2) * 64 + lane], wf[(ntl * 2) * 64 + lane], acc, 0, 0, 0);
          acc = MFMA(xnf[(mt * 2 + 1) * 64 + lane], wf[(ntl * 2 + 1) * 64 + lane], acc, 0, 0, 0);
          if (mt < 2) {
            float* p = dst + (mt * 16 + lq * 4) * 68 + n;
            p[0] = acc[0]; p[68] = acc[1]; p[136] = acc[2]; p[204] = acc[3];
          } else if (lq == 0) {
            float* p = dst + 32 * 68 + n;
            p[0] = acc[0]; p[68] = acc[1];
          }
        }
      }
      // phase V: transposed bf16 store, n = w*16+ln in 0..127
      {
        const bf16x8* wf = FRB + LB + 1024;
        int n = w * 16 + ln;
#pragma unroll
        for (int mt = 0; mt < 3; ++mt) {
          f32x4 acc = {0.f, 0.f, 0.f, 0.f};
          acc = MFMA(xnf[(mt * 2) * 64 + lane], wf[(w * 2) * 64 + lane], acc, 0, 0, 0);
          acc = MFMA(xnf[(mt * 2 + 1) * 64 + lane], wf[(w * 2 + 1) * 64 + lane], acc, 0, 0, 0);
          if (mt == 0) {  // img0, t = lq*4..+3: one b64 store
            uint2 uv;
            uv.x = pack_bf2(acc[0], acc[1]);
            uv.y = pack_bf2(acc[2], acc[3]);
            *(uint2*)(sVbT + n * 20 + lq * 4) = uv;
          } else if (mt == 1) {  // straddles image boundary
#pragma unroll
            for (int i = 0; i < 4; ++i) {
              int m = 16 + lq * 4 + i;
              int img = (m >= 17), t = m - img * 17;
              sVbT[img * 2560 + n * 20 + t] = cvt_bf(acc[i]);
            }
          } else if (lq == 0) {  // m=32,33 -> img1 t=15,16
            sVbT[2560 + n * 20 + 15] = cvt_bf(acc[0]);
            sVbT[2560 + n * 20 + 16] = cvt_bf(acc[1]);
          }
        }
      }
      // phase G: row-major bf16, n = w*16+ln in 0..127
      {
        const bf16x8* wf = FRB + LB + 2048;
        int n = w * 16 + ln;
#pragma unroll
        for (int mt = 0; mt < 3; ++mt) {
          f32x4 acc = {0.f, 0.f, 0.f, 0.f};
          acc = MFMA(xnf[(mt * 2) * 64 + lane], wf[(w * 2) * 64 + lane], acc, 0, 0, 0);
          acc = MFMA(xnf[(mt * 2 + 1) * 64 + lane], wf[(w * 2 + 1) * 64 + lane], acc, 0, 0, 0);
          if (mt < 2) {
            unsigned short* p = sGb + (mt * 16 + lq * 4) * 136 + n;
            p[0] = cvt_bf(acc[0]); p[136] = cvt_bf(acc[1]);
            p[272] = cvt_bf(acc[2]); p[408] = cvt_bf(acc[3]);
          } else if (lq == 0) {
            sGb[32 * 136 + n] = cvt_bf(acc[0]);
            sGb[33 * 136 + n] = cvt_bf(acc[1]);
          }
        }
      }
    }
    __syncthreads();

    // ---- scores via MFMA 32x32x16: 8 jobs (img, head), rotary fused in frag build ----
    {
      int img = w >> 2, hh = w & 3;
      int cl = lane & 31, kh = lane >> 5;
      int tt = (cl < 17) ? cl : 16;  // clamp garbage rows (discarded at store)
      int rb = (img * 17 + tt) * 68 + hh * 16 + kh * 8;
      int sb = tt * 16 + kh * 8;
      float4 s0 = *(const float4*)(sSin + sb), s1 = *(const float4*)(sSin + sb + 4);
      float4 c0 = *(const float4*)(sCos + sb), c1 = *(const float4*)(sCos + sb + 4);
      float4 qa = *(const float4*)(sQ + rb), qb = *(const float4*)(sQ + rb + 4);
      i32x4 ap;
      ap.x = pack_bf2(qa.x * c0.x - qa.y * s0.x, qa.y * c0.y + qa.x * s0.y);
      ap.y = pack_bf2(qa.z * c0.z - qa.w * s0.z, qa.w * c0.w + qa.z * s0.w);
      ap.z = pack_bf2(qb.x * c1.x - qb.y * s1.x, qb.y * c1.y + qb.x * s1.y);
      ap.w = pack_bf2(qb.z * c1.z - qb.w * s1.z, qb.w * c1.w + qb.z * s1.w);
      float4 ka = *(const float4*)(sK + rb), kb = *(const float4*)(sK + rb + 4);
      i32x4 bp;
      bp.x = pack_bf2(ka.x * c0.x - ka.y * s0.x, ka.y * c0.y + ka.x * s0.y);
      bp.y = pack_bf2(ka.z * c0.z - ka.w * s0.z, ka.w * c0.w + ka.z * s0.w);
      bp.z = pack_bf2(kb.x * c1.x - kb.y * s1.x, kb.y * c1.y + kb.x * s1.y);
      bp.w = pack_bf2(kb.z * c1.z - kb.w * s1.z, kb.w * c1.w + kb.z * s1.w);
      f32x16 acc = {0.f, 0.f, 0.f, 0.f, 0.f, 0.f, 0.f, 0.f,
                    0.f, 0.f, 0.f, 0.f, 0.f, 0.f, 0.f, 0.f};
      acc = MFMA32(as_bf(ap), as_bf(bp), acc, 0, 0, 0);
      if (cl < 17) {  // valid u column; dmask (incl 0.25) zeroes u>t
        int scb = img * 1360 + hh * 340;
        const float* dmb = sDM + hh * 289;
#pragma unroll
        for (int r = 0; r < 16; ++r) {
          int t = (r & 3) + 8 * (r >> 2) + 4 * kh;
          if (t < 17) sSC[scb + t * 20 + cl] = acc[r] * dmb[t * 17 + cl];
        }
      }
    }
    __syncthreads();

    // ---- denominators ----
    if (tid < 136) {
      const float* base = sSC + tid * 20;
      float s = 0.f;
      for (int u = 0; u < 17; ++u) s += base[u];
      float den = fabsf(s);
      if (den < 1.f) den = 1.f;
      sST[68 + tid] = 1.f / den;
    }
    __syncthreads();

    // ---- AV via MFMA 32x32x16: 8 jobs (img, head), one per wave ----
    {
      int img = w >> 2, hh = w & 3;
      int cl = lane & 31, kh = lane >> 5;   // cl: A-row t / B-col c; kh: k-half
      int tt = (cl < 17) ? cl : 16;         // clamp invalid rows (discarded at store)
      const float* scb = sSC + img * 1360 + hh * 340;
      float den = sST[68 + img * 68 + hh * 17 + tt];
      const float4* a4 = (const float4*)(scb + tt * 20 + kh * 8);
      float4 av0 = a4[0], av1 = a4[1];
      i32x4 ap;
      ap.x = pack_bf2(av0.x * den, av0.y * den);
      ap.y = pack_bf2(av0.z * den, av0.w * den);
      ap.z = pack_bf2(av1.x * den, av1.y * den);
      ap.w = pack_bf2(av1.z * den, av1.w * den);
      const unsigned short* vcol = sVbT + img * 2560 + (hh * 32 + cl) * 20 + kh * 8;
      const uint2* vq = (const uint2*)vcol;
      uint2 v0 = vq[0], v1 = vq[1];
      i32x4 bp; bp.x = (int)v0.x; bp.y = (int)v0.y; bp.z = (int)v1.x; bp.w = (int)v1.y;
      f32x16 acc = {0.f, 0.f, 0.f, 0.f, 0.f, 0.f, 0.f, 0.f,
                    0.f, 0.f, 0.f, 0.f, 0.f, 0.f, 0.f, 0.f};
      acc = MFMA32(as_bf(ap), as_bf(bp), acc, 0, 0, 0);
      i32x4 a1 = {0, 0, 0, 0}, b1v = {0, 0, 0, 0};
      if (kh == 0) {  // u = 16 tail
        float s16 = scb[tt * 20 + 16] * den;
        a1.x = (int)(unsigned)cvt_bf(s16);
        b1v.x = (int)(unsigned)sVbT[img * 2560 + (hh * 32 + cl) * 20 + 16];
      }
      acc = MFMA32(as_bf(a1), as_bf(b1v), acc, 0, 0, 0);
      int cg = hh * 32 + cl;
#pragma unroll
      for (int r = 0; r < 16; ++r) {
        int t = (r & 3) + 8 * (r >> 2) + 4 * kh;
        if (t < 17) sO[(img * 17 + t) * 130 + cg] = acc[r];
      }
    }
    __syncthreads();

    // ---- group norm stats: 2 lanes per row ----
    if (tid < 272) {
      int row = tid >> 1, sub = tid & 1;  // row = img*68 + hh*17 + t
      int img = row / 68, hr = row % 68, hh = hr / 17, t = hr % 17;
      int m = img * 17 + t;
      const float2* op = (const float2*)(sO + m * 130 + hh * 32 + sub * 16);
      float s1 = 0.f, s2 = 0.f;
#pragma unroll
      for (int i = 0; i < 8; ++i) {
        float2 v = op[i];
        s1 += v.x; s2 += v.x * v.x;
        s1 += v.y; s2 += v.y * v.y;
      }
      s1 += __shfl_xor(s1, 1); s2 += __shfl_xor(s2, 1);
      if (sub == 0) {
        float mu = s1 * (1.f / 32.f);
        float var = s2 * (1.f / 32.f) - mu * mu;
        sST[204 + row] = mu;
        sST[340 + row] = rsqrtf(var + 1e-5f);
      }
    }
    __syncthreads();

    // ---- groupnorm + silu gate -> OA frags ----
    for (int s = tid; s < 768; s += 512) {
      int mt = s >> 8, kt = (s >> 6) & 3, la = s & 63;
      int q = la >> 4, m = mt * 16 + (la & 15);
      int cb = kt * 32 + q * 8;
      i32x4 pk = {0, 0, 0, 0};
      if (m < 34) {
        int img = (m >= 17), t = m - img * 17;
        int sti = img * 68 + kt * 17 + t;
        float mu = sST[204 + sti], rr = sST[340 + sti];
        const float2* op = (const float2*)(sO + m * 130 + cb);
        i32x4 gu = *(const i32x4*)(sGb + m * 136 + cb);
        float vv[8];
#pragma unroll
        for (int q2 = 0; q2 < 4; ++q2) {
          float2 ov = op[q2];
          unsigned gw = (q2 == 0) ? (unsigned)gu.x : (q2 == 1) ? (unsigned)gu.y
                       : (q2 == 2) ? (unsigned)gu.z : (unsigned)gu.w;
          float2 gv = unpk(gw);
          float on0 = (ov.x - mu) * rr;
          float on1 = (ov.y - mu) * rr;
          vv[2 * q2]     = on0 * (gv.x / (1.f + __expf(-gv.x)));
          vv[2 * q2 + 1] = on1 * (gv.y / (1.f + __expf(-gv.y)));
        }
        pk.x = pack_bf2(vv[0], vv[1]); pk.y = pack_bf2(vv[2], vv[3]);
        pk.z = pack_bf2(vv[4], vv[5]); pk.w = pack_bf2(vv[6], vv[7]);
      }
      ((i32x4*)(sm + O_SCA))[s] = pk;
    }
    __syncthreads();

    // ---- Wo MFMA: 12 jobs / 8 waves; += residual ----
    {
      const bf16x8* oaf = (const bf16x8*)(sm + O_SCA);
      const bf16x8* wof = FRB + LB + 3072;
      for (int j = w; j < 12; j += 8) {
        int mt = j >> 2, nt = j & 3;
        f32x4 acc = {0.f, 0.f, 0.f, 0.f};
#pragma unroll
        for (int kt = 0; kt < 4; ++kt)
          acc = MFMA(oaf[(mt * 4 + kt) * 64 + lane], wof[(nt * 4 + kt) * 64 + lane], acc, 0, 0, 0);
        int n = nt * 16 + ln;
#pragma unroll
        for (int i = 0; i < 4; ++i) {
          int m = mt * 16 + lq * 4 + i;
          if (m < 34) sH[m * 66 + n] += acc[i];
        }
      }
    }
    __syncthreads();

    // ---- ln2 stats ----
    if (tid < 272) {
      int m = tid >> 3, sub = tid & 7;
      const float2* hp = (const float2*)(sH + m * 66 + sub * 8);
      float s1 = 0.f, s2 = 0.f;
#pragma unroll
      for (int i = 0; i < 4; ++i) {
        float2 v = hp[i];
        s1 += v.x; s2 += v.x * v.x;
        s1 += v.y; s2 += v.y * v.y;
      }
      s1 += __shfl_xor(s1, 1); s2 += __shfl_xor(s2, 1);
      s1 += __shfl_xor(s1, 2); s2 += __shfl_xor(s2, 2);
      s1 += __shfl_xor(s1, 4); s2 += __shfl_xor(s2, 4);
      if (sub == 0) {
        float mu = s1 * (1.f / 64.f);
        float var = s2 * (1.f / 64.f) - mu * mu;
        sST[m] = mu;
        sST[34 + m] = rsqrtf(var + 1e-5f);
      }
    }
    __syncthreads();

    // ---- ln2 -> XN2 A-frags (bf16) ----
    if (tid < 384) {
      int s = tid;
      int mt = s >> 7, kt = (s >> 6) & 1, la = s & 63;
      int m = mt * 16 + (la & 15), q = la >> 4;
      int kb = kt * 32 + q * 8;
      i32x4 pk = {0, 0, 0, 0};
      if (m < 34) {
        float mu = sST[m], rr = sST[34 + m];
        float vv[8];
#pragma unroll
        for (int t2 = 0; t2 < 8; t2 += 2) {
          float2 sv = ld2<BF16>(ln2s, l * 64 + kb + t2);
          float2 bv = ld2<BF16>(ln2b, l * 64 + kb + t2);
          vv[t2]     = (sH[m * 66 + kb + t2] - mu) * rr * sv.x + bv.x;
          vv[t2 + 1] = (sH[m * 66 + kb + t2 + 1] - mu) * rr * sv.y + bv.y;
        }
        pk.x = pack_bf2(vv[0], vv[1]); pk.y = pack_bf2(vv[2], vv[3]);
        pk.z = pack_bf2(vv[4], vv[5]); pk.w = pack_bf2(vv[6], vv[7]);
      }
      ((i32x4*)(sm + O_XNF))[s] = pk;
    }
    __syncthreads();

    // ---- FFN1 via MFMA: 3 jobs (mt), N=12 in one 16-tile, K=64; gelu at store ----
    if (w < 3) {
      const bf16x8* xnf = (const bf16x8*)(sm + O_XNF);
      const bf16x8* w1f = FRB + 35072 + l * 384;
      int mt = w;
      f32x4 acc = {0.f, 0.f, 0.f, 0.f};
#pragma unroll
      for (int kt = 0; kt < 2; ++kt)
        acc = MFMA(xnf[(mt * 2 + kt) * 64 + lane], w1f[kt * 64 + lane], acc, 0, 0, 0);
      if (ln < 12) {
        float b = ld<BF16>(b1, l * 12 + ln);
#pragma unroll
        for (int i = 0; i < 4; ++i) {
          int m = mt * 16 + lq * 4 + i;
          if (m < 34) {
            float a = acc[i] + b;
            float inner = 0.7978845608028654f * (a + 0.044715f * a * a * a);
            float e = __expf(2.f * inner);
            float th = 1.f - 2.f / (e + 1.f);
            sFF[m * 12 + ln] = 0.5f * a * (1.f + th);
          }
        }
      }
    }
    __syncthreads();

    // ---- FFN2 via MFMA: 12 jobs (mt3 x nt4), K=32 (e padded); bias+residual at store ----
    {
      const bf16x8* w2f = FRB + 35072 + l * 384 + 128;
      for (int j = w; j < 12; j += 8) {
        int mt = j >> 2, nt = j & 3;
        i32x4 ap = {0, 0, 0, 0};
        int ma = mt * 16 + ln;
        if (ma < 34) {
          const float* fp = sFF + ma * 12;
          if (lq == 0) {
            ap.x = pack_bf2(fp[0], fp[1]); ap.y = pack_bf2(fp[2], fp[3]);
            ap.z = pack_bf2(fp[4], fp[5]); ap.w = pack_bf2(fp[6], fp[7]);
          } else if (lq == 1) {
            ap.x = pack_bf2(fp[8], fp[9]); ap.y = pack_bf2(fp[10], fp[11]);
          }
        }
        f32x4 acc = {0.f, 0.f, 0.f, 0.f};
        acc = MFMA(as_bf(ap), w2f[nt * 64 + lane], acc, 0, 0, 0);
        int n = nt * 16 + ln;
        float b = ld<BF16>(b2, l * 64 + n);
#pragma unroll
        for (int i = 0; i < 4; ++i) {
          int m = mt * 16 + lq * 4 + i;
          if (m < 34) sH[m * 66 + n] += acc[i] + b;
        }
      }
    }
    __syncthreads();
  }

  // ---- final: lnf (last token each image), neck, head ----
  if (tid < 2) {
    int m = tid * 17 + 16;
    float s1 = 0.f, s2 = 0.f;
    for (int d = 0; d < 64; ++d) {
      float v = sH[m * 66 + d];
      s1 += v; s2 += v * v;
    }
    float mu = s1 * (1.f / 64.f);
    float var = s2 * (1.f / 64.f) - mu * mu;
    sST[tid] = mu;
    sST[2 + tid] = rsqrtf(var + 1e-5f);
  }
  __syncthreads();
  if (tid < 32) {
    int img = tid >> 4, jn = tid & 15;
    int m = img * 17 + 16;
    float mu = sST[img], rr = sST[2 + img];
    float acc = ld<BF16>(neckb, jn);
    for (int d = 0; d < 64; ++d) {
      float yn = (sH[m * 66 + d] - mu) * rr * ld<BF16>(lnfs, d) + ld<BF16>(lnfb, d);
      acc += yn * ld<BF16>(neckw, d * 16 + jn);
    }
    sST[8 + img * 16 + jn] = acc;
  }
  __syncthreads();
  if (tid < 20) {
    int img = tid / 10, o = tid % 10;
    float acc = ld<BF16>(headb, o);
#pragma unroll
    for (int e = 0; e < 16; ++e) acc += sST[8 + img * 16 + e] * ld<BF16>(headw, e * 10 + o);
    if (BF16) {
      ((__hip_bfloat16*)out)[(img0 + img) * 10 + o] = __float2bfloat16(acc);
    } else {
      ((float*)out)[(img0 + img) * 10 + o] = acc;
    }
  }
}

extern "C" void kernel_launch(void* const* d_in, const int* in_sizes, int n_in,
                              void* d_out, int out_size, void* d_ws, size_t ws_size,
                              hipStream_t stream) {
  float* tab = (float*)d_ws;
  unsigned short* frag = (unsigned short*)((char*)d_ws + 8192);

  setup_tables<<<dim3(1), dim3(256), 0, stream>>>(tab, d_in[0]);

  const int prepBlocks = (FRAG_TOT + 255) / 256;
  prep_frags<false><<<dim3(prepBlocks), dim3(256), 0, stream>>>(
      d_in[1], d_in[5], d_in[6], d_in[7], d_in[8], d_in[9], d_in[12], d_in[14], tab, frag);
  prep_frags<true><<<dim3(prepBlocks), dim3(256), 0, stream>>>(
      d_in[1], d_in[5], d_in[6], d_in[7], d_in[8], d_in[9], d_in[12], d_in[14], tab, frag);

  const int B = in_sizes[0] / 3072;
  const int grid = B / 2;

  vit_fused<false><<<dim3(grid), dim3(512), 0, stream>>>(
      d_in[0], d_in[2], d_in[3], d_in[4], d_in[10], d_in[11], d_in[13],
      d_in[15], d_in[16], d_in[17], d_in[18], d_in[19], d_in[20], d_in[21],
      d_in[22], d_in[23], tab, frag, d_out);
  vit_fused<true><<<dim3(grid), dim3(512), 0, stream>>>(
      d_in[0], d_in[2], d_in[3], d_in[4], d_in[10], d_in[11], d_in[13],
      d_in[15], d_in[16], d_in[17], d_in[18], d_in[19], d_in[20], d_in[21],
      d_in[22], d_in[23], tab, frag, d_out);
}

// Round 7
// 791.101 us; speedup vs baseline: 1.5516x; 1.0461x over previous
//
#include <hip/hip_runtime.h>
#include <hip/hip_bf16.h>

#define NLAY 8
#define MFMA __builtin_amdgcn_mfma_f32_16x16x32_bf16
#define MFMA32 __builtin_amdgcn_mfma_f32_32x32x16_bf16

typedef __attribute__((ext_vector_type(8))) short bf16x8;
typedef __attribute__((ext_vector_type(4))) float f32x4;
typedef __attribute__((ext_vector_type(16))) float f32x16;
typedef __attribute__((ext_vector_type(4))) int i32x4;

template <bool BF16>
__device__ __forceinline__ float ld(const void* p, int i) {
  if (BF16) {
    unsigned short u = ((const unsigned short*)p)[i];
    return __uint_as_float(((unsigned)u) << 16);
  }
  return ((const float*)p)[i];
}

template <bool BF16>
__device__ __forceinline__ float2 ld2(const void* p, int i) {  // i even
  float2 r;
  if (BF16) {
    unsigned u = ((const unsigned*)p)[i >> 1];
    r.x = __uint_as_float(u << 16);
    r.y = __uint_as_float(u & 0xffff0000u);
  } else {
    r = ((const float2*)p)[i >> 1];
  }
  return r;
}

__device__ __forceinline__ unsigned pack_bf2(float a, float b) {
  __hip_bfloat16 ha = __float2bfloat16(a), hb = __float2bfloat16(b);
  unsigned short ua, ub;
  __builtin_memcpy(&ua, &ha, 2);
  __builtin_memcpy(&ub, &hb, 2);
  return ((unsigned)ub << 16) | (unsigned)ua;
}

__device__ __forceinline__ unsigned short cvt_bf(float a) {
  __hip_bfloat16 h = __float2bfloat16(a);
  unsigned short us;
  __builtin_memcpy(&us, &h, 2);
  return us;
}

__device__ __forceinline__ float2 unpk(unsigned u) {
  float2 r;
  r.x = __uint_as_float(u << 16);
  r.y = __uint_as_float(u & 0xffff0000u);
  return r;
}

__device__ __forceinline__ bf16x8 as_bf(i32x4 v) {
  bf16x8 r;
  __builtin_memcpy(&r, &v, 16);
  return r;
}

// ws[0..271]=sin, ws[272..543]=cos, ws[544..1699]=dmask, ws[1700]=dtype flag
__global__ void setup_tables(float* __restrict__ ws, const void* __restrict__ x) {
  int tid = threadIdx.x;
  for (int idx = tid; idx < 272; idx += 256) {
    int t = idx >> 4, j = idx & 15;
    float a = powf(10000.f, -(float)(j >> 1) / 7.f);
    float arg = (float)t * a;
    ws[idx] = sinf(arg);
    ws[272 + idx] = cosf(arg);
  }
  for (int row = tid; row < 68; row += 256) {
    int hh = row / 17, t = row % 17;
    float gamma = 1.f - exp2f(-5.f - 4.f * (float)hh / 3.f);
    float sum = 0.f;
    for (int u = 0; u <= t; ++u) sum += powf(gamma, (float)(t - u));
    float rn = rsqrtf(sum);
    for (int u = 0; u < 17; ++u)
      ws[544 + row * 17 + u] = (u <= t) ? powf(gamma, (float)(t - u)) * rn : 0.f;
  }
  if (tid == 0) {
    const unsigned short* u16 = (const unsigned short*)x;
    int sane = 0;
    for (int i = 0; i < 128; ++i) {
      float v = __uint_as_float(((unsigned)u16[2 * i]) << 16);
      float av = fabsf(v);
      if (v == 0.f || (av > 1e-8f && av < 1e4f)) sane++;
    }
    ws[1700] = (sane >= 64) ? 1.f : 0.f;
  }
}

// Pre-swizzle weights into MFMA B-fragment order (bf16), into ws+8192 bytes.
#define FRAG_OLD 280576
#define FRAG_TOT 305152
template <bool BF16>
__global__ void prep_frags(const void* __restrict__ patch_w,
                           const void* __restrict__ Wq, const void* __restrict__ Wk,
                           const void* __restrict__ Wv, const void* __restrict__ Wg,
                           const void* __restrict__ Wo, const void* __restrict__ w1,
                           const void* __restrict__ w2,
                           const float* __restrict__ tab,
                           unsigned short* __restrict__ frag) {
  if ((tab[1700] > 0.5f) != BF16) return;
  int g = blockIdx.x * 256 + threadIdx.x;
  if (g >= FRAG_TOT) return;
  float v;
  if (g < 12288) {  // patch_w: K=192 (kt6), N=64 (nt4)
    int nt = g / 3072, r = g % 3072, kt = r / 512, r2 = r % 512, la = r2 >> 3, j = r2 & 7;
    int n = nt * 16 + (la & 15), k = kt * 32 + (la >> 4) * 8 + j;
    v = ld<BF16>(patch_w, k * 64 + n);
  } else if (g < FRAG_OLD) {
    int gg = g - 12288, l = gg / 33536, o = gg % 33536;
    if (o < 8192) {  // Wq / Wk
      const void* W = (o < 4096) ? Wq : Wk;
      int e = o & 4095;
      int nt = e / 1024, r = e % 1024, kt = r / 512, r2 = r % 512, la = r2 >> 3, j = r2 & 7;
      int n = nt * 16 + (la & 15), k = kt * 32 + (la >> 4) * 8 + j;
      v = ld<BF16>(W, l * 4096 + k * 64 + n);
    } else if (o < 24576) {  // Wv / Wg
      const void* W = (o < 16384) ? Wv : Wg;
      int e = (o - 8192) & 8191;
      int nt = e / 1024, r = e % 1024, kt = r / 512, r2 = r % 512, la = r2 >> 3, j = r2 & 7;
      int n = nt * 16 + (la & 15), k = kt * 32 + (la >> 4) * 8 + j;
      v = ld<BF16>(W, l * 8192 + k * 128 + n);
    } else if (o < 32768) {  // Wo
      int e = o - 24576;
      int nt = e / 2048, r = e % 2048, kt = r / 512, r2 = r % 512, la = r2 >> 3, j = r2 & 7;
      int n = nt * 16 + (la & 15), k = kt * 32 + (la >> 4) * 8 + j;
      v = ld<BF16>(Wo, l * 8192 + k * 64 + n);
    } else {  // legacy w1T (unused)
      int e = o - 32768, eo = e / 64, d = e % 64;
      v = ld<BF16>(w1, l * 768 + d * 12 + eo);
    }
  } else {  // w1 / w2 B-frags
    int gg = g - FRAG_OLD, l = gg / 3072, o = gg % 3072;
    if (o < 1024) {  // w1 B-frag: n=e (pad>=12), k=d, kt 0..1
      int kt = o >> 9, r = o & 511, la = r >> 3, j = r & 7;
      int n = la & 15, k = kt * 32 + (la >> 4) * 8 + j;
      v = (n < 12) ? ld<BF16>(w1, l * 768 + k * 12 + n) : 0.f;
    } else {  // w2 B-frag: n=d (nt 0..3), k=e (pad>=12), K=32
      int e2 = o - 1024;
      int nt = e2 >> 9, r = e2 & 511, la = r >> 3, j = r & 7;
      int n = nt * 16 + (la & 15), k = (la >> 4) * 8 + j;
      v = (k < 12) ? ld<BF16>(w2, (l * 12 + k) * 64 + n) : 0.f;
    }
  }
  __hip_bfloat16 h = __float2bfloat16(v);
  unsigned short us;
  __builtin_memcpy(&us, &h, 2);
  frag[g] = us;
}

// LDS float offsets
#define O_DM   0      // 1156 (dmask * 0.25 folded)
#define O_SIN  1156   // 272
#define O_COS  1428   // 272
#define O_ST   1700   // 512
#define O_H    2212   // 2244: H fp32 34x66
#define O_XNF  4456   // 1536: XN A-frags (ln1 / ln2)
#define O_FF   5992   // 408
#define O_R    6400   // 4624: Q 34x68 + K 34x68 / alias O fp32 34x130
#define O_SCA  11024  // 3072: patch A-frags / SC fp32 2x4x17x20 (2720) / OA frags
#define O_VG   14096  // 4872: VT bf16 2x128x20 (2560 f) + G bf16 34x136 (2312 f)
#define SM_TOT 18968

template <bool BF16>
__global__ void __launch_bounds__(512, 4)
vit_fused(const void* __restrict__ x, const void* __restrict__ patch_b,
          const void* __restrict__ cls, const void* __restrict__ pos,
          const void* __restrict__ ln1s, const void* __restrict__ ln1b,
          const void* __restrict__ b1, const void* __restrict__ b2,
          const void* __restrict__ ln2s, const void* __restrict__ ln2b,
          const void* __restrict__ lnfs, const void* __restrict__ lnfb,
          const void* __restrict__ neckw, const void* __restrict__ neckb,
          const void* __restrict__ headw, const void* __restrict__ headb,
          const float* __restrict__ tab, const unsigned short* __restrict__ FR,
          void* __restrict__ out) {
  if ((tab[1700] > 0.5f) != BF16) return;

  const int tid = threadIdx.x;
  const int lane = tid & 63, w = tid >> 6;  // w in 0..7
  const int lq = lane >> 4, ln = lane & 15;
  const int img0 = 2 * blockIdx.x;

  __shared__ __align__(16) float sm[SM_TOT];
  float* sDM  = sm + O_DM;
  float* sSin = sm + O_SIN;
  float* sCos = sm + O_COS;
  float* sST  = sm + O_ST;
  float* sH   = sm + O_H;
  float* sFF  = sm + O_FF;
  float* sQ   = sm + O_R;          // 34x68
  float* sK   = sm + O_R + 2312;   // 34x68
  float* sO   = sm + O_R;          // alias, 34x130
  float* sSC  = sm + O_SCA;        // 2 x 4 x 17 x 20 (pitch-20 rows)
  unsigned short* sVbT = (unsigned short*)(sm + O_VG);          // 2 x 128 x 20 (c-major, t inner)
  unsigned short* sGb  = (unsigned short*)(sm + O_VG) + 5120;   // 34x136
  const bf16x8* FRB = (const bf16x8*)FR;

  // ---- stage tables + patch A-frags + cls rows ----
  for (int i = tid; i < 1156; i += 512) sDM[i] = tab[544 + i] * 0.25f;  // K-scale folded
  for (int i = tid; i < 272; i += 512) { sSin[i] = tab[i]; sCos[i] = tab[272 + i]; }
  for (int s = tid; s < 768; s += 512) {  // patch A-frags into O_SCA
    int mt = s / 384, r = s % 384, kt = r / 64, la = r % 64;
    int p = la & 15, q = la >> 4;
    int kb = kt * 32 + q * 8;
    int c = kb >> 6, rem = kb & 63, a = rem >> 3;
    int pi = p >> 2, pj = p & 3;
    int src = (img0 + mt) * 3072 + c * 1024 + (pi * 8 + a) * 32 + pj * 8;
    float v[8];
#pragma unroll
    for (int t2 = 0; t2 < 8; t2 += 2) {
      float2 pv = ld2<BF16>(x, src + t2);
      v[t2] = pv.x; v[t2 + 1] = pv.y;
    }
    i32x4 pk;
    pk.x = pack_bf2(v[0], v[1]); pk.y = pack_bf2(v[2], v[3]);
    pk.z = pack_bf2(v[4], v[5]); pk.w = pack_bf2(v[6], v[7]);
    ((i32x4*)(sm + O_SCA))[s] = pk;
  }
  if (tid < 128) {  // cls token rows
    int img = tid >> 6, n = tid & 63;
    sH[(img * 17) * 66 + n] = ld<BF16>(cls, n) + ld<BF16>(pos, n);
  }
  __syncthreads();

  // ---- patch embed MFMA: 8 jobs = 2mt x 4nt, one per wave ----
  {
    int mt = w >> 2, nt = w & 3;
    f32x4 acc = {0.f, 0.f, 0.f, 0.f};
    const bf16x8* paf = (const bf16x8*)(sm + O_SCA);
#pragma unroll
    for (int kt = 0; kt < 6; ++kt)
      acc = MFMA(paf[(mt * 6 + kt) * 64 + lane], FRB[(nt * 6 + kt) * 64 + lane], acc, 0, 0, 0);
    int n = nt * 16 + ln;
    float pb = ld<BF16>(patch_b, n);
#pragma unroll
    for (int i = 0; i < 4; ++i) {
      int t = 1 + lq * 4 + i;
      sH[(mt * 17 + t) * 66 + n] = acc[i] + pb + ld<BF16>(pos, t * 64 + n);
    }
  }
  __syncthreads();

  for (int l = 0; l < NLAY; ++l) {
    const int LB = 1536 + l * 4192;  // layer base, bf16x8 slots

    // ---- ln1: fused wave-local stats + A-frag build (8 lanes/row) ----
    if (tid < 320) {
      int m = tid >> 3, sub = tid & 7;
      i32x4 pk = {0, 0, 0, 0};
      if (m < 34) {
        const float2* hp = (const float2*)(sH + m * 66 + sub * 8);
        float2 h0 = hp[0], h1 = hp[1], h2 = hp[2], h3 = hp[3];
        float s1 = 0.f, s2 = 0.f;
        s1 += h0.x; s2 += h0.x * h0.x; s1 += h0.y; s2 += h0.y * h0.y;
        s1 += h1.x; s2 += h1.x * h1.x; s1 += h1.y; s2 += h1.y * h1.y;
        s1 += h2.x; s2 += h2.x * h2.x; s1 += h2.y; s2 += h2.y * h2.y;
        s1 += h3.x; s2 += h3.x * h3.x; s1 += h3.y; s2 += h3.y * h3.y;
        s1 += __shfl_xor(s1, 1); s2 += __shfl_xor(s2, 1);
        s1 += __shfl_xor(s1, 2); s2 += __shfl_xor(s2, 2);
        s1 += __shfl_xor(s1, 4); s2 += __shfl_xor(s2, 4);
        float mu = s1 * (1.f / 64.f);
        float var = s2 * (1.f / 64.f) - mu * mu;
        float rr = rsqrtf(var + 1e-5f);
        int kb = sub * 8;
        float hv[8] = {h0.x, h0.y, h1.x, h1.y, h2.x, h2.y, h3.x, h3.y};
        float vv[8];
#pragma unroll
        for (int t2 = 0; t2 < 8; t2 += 2) {
          float2 sv = ld2<BF16>(ln1s, l * 64 + kb + t2);
          float2 bv = ld2<BF16>(ln1b, l * 64 + kb + t2);
          vv[t2]     = (hv[t2] - mu) * rr * sv.x + bv.x;
          vv[t2 + 1] = (hv[t2 + 1] - mu) * rr * sv.y + bv.y;
        }
        pk.x = pack_bf2(vv[0], vv[1]); pk.y = pack_bf2(vv[2], vv[3]);
        pk.z = pack_bf2(vv[4], vv[5]); pk.w = pack_bf2(vv[6], vv[7]);
      }
      int slot = (m >> 4) * 128 + (sub >> 2) * 64 + (sub & 3) * 16 + (m & 15);
      ((i32x4*)(sm + O_XNF))[slot] = pk;
    }
    __syncthreads();

    // ---- QKVG MFMA: 3 phases (QK / V / G) x 3 mt, specialized stores ----
    {
      const bf16x8* xnf = (const bf16x8*)(sm + O_XNF);
      // phase QK: waves 0-3 -> Q, waves 4-7 -> K
      {
        const bf16x8* wf = FRB + LB + ((w < 4) ? 0 : 512);
        float* dst = (w < 4) ? sQ : sK;
        int ntl = w & 3;
        int n = ntl * 16 + ln;
#pragma unroll
        for (int mt = 0; mt < 3; ++mt) {
          f32x4 acc = {0.f, 0.f, 0.f, 0.f};
          acc = MFMA(xnf[(mt * 2) * 64 + lane], wf[(ntl * 2) * 64 + lane], acc, 0, 0, 0);
          acc = MFMA(xnf[(mt * 2 + 1) * 64 + lane], wf[(ntl * 2 + 1) * 64 + lane], acc, 0, 0, 0);
          if (mt < 2) {
            float* p = dst + (mt * 16 + lq * 4) * 68 + n;
            p[0] = acc[0]; p[68] = acc[1]; p[136] = acc[2]; p[204] = acc[3];
          } else if (lq == 0) {
            float* p = dst + 32 * 68 + n;
            p[0] = acc[0]; p[68] = acc[1];
          }
        }
      }
      // phase V: transposed bf16 store, n = w*16+ln in 0..127
      {
        const bf16x8* wf = FRB + LB + 1024;
        int n = w * 16 + ln;
#pragma unroll
        for (int mt = 0; mt < 3; ++mt) {
          f32x4 acc = {0.f, 0.f, 0.f, 0.f};
          acc = MFMA(xnf[(mt * 2) * 64 + lane], wf[(w * 2) * 64 + lane], acc, 0, 0, 0);
          acc = MFMA(xnf[(mt * 2 + 1) * 64 + lane], wf[(w * 2 + 1) * 64 + lane], acc, 0, 0, 0);
          if (mt == 0) {  // img0, t = lq*4..+3: one b64 store
            uint2 uv;
            uv.x = pack_bf2(acc[0], acc[1]);
            uv.y = pack_bf2(acc[2], acc[3]);
            *(uint2*)(sVbT + n * 20 + lq * 4) = uv;
          } else if (mt == 1) {  // straddles image boundary
#pragma unroll
            for (int i = 0; i < 4; ++i) {
              int m = 16 + lq * 4 + i;
              int img = (m >= 17), t = m - img * 17;
              sVbT[img * 2560 + n * 20 + t] = cvt_bf(acc[i]);
            }
          } else if (lq == 0) {  // m=32,33 -> img1 t=15,16
            sVbT[2560 + n * 20 + 15] = cvt_bf(acc[0]);
            sVbT[2560 + n * 20 + 16] = cvt_bf(acc[1]);
          }
        }
      }
      // phase G: row-major bf16, n = w*16+ln in 0..127
      {
        const bf16x8* wf = FRB + LB + 2048;
        int n = w * 16 + ln;
#pragma unroll
        for (int mt = 0; mt < 3; ++mt) {
          f32x4 acc = {0.f, 0.f, 0.f, 0.f};
          acc = MFMA(xnf[(mt * 2) * 64 + lane], wf[(w * 2) * 64 + lane], acc, 0, 0, 0);
          acc = MFMA(xnf[(mt * 2 + 1) * 64 + lane], wf[(w * 2 + 1) * 64 + lane], acc, 0, 0, 0);
          if (mt < 2) {
            unsigned short* p = sGb + (mt * 16 + lq * 4) * 136 + n;
            p[0] = cvt_bf(acc[0]); p[136] = cvt_bf(acc[1]);
            p[272] = cvt_bf(acc[2]); p[408] = cvt_bf(acc[3]);
          } else if (lq == 0) {
            sGb[32 * 136 + n] = cvt_bf(acc[0]);
            sGb[33 * 136 + n] = cvt_bf(acc[1]);
          }
        }
      }
    }
    __syncthreads();

    // ---- scores via MFMA 32x32x16: 8 jobs (img, head), rotary fused in frag build ----
    {
      int img = w >> 2, hh = w & 3;
      int cl = lane & 31, kh = lane >> 5;
      int tt = (cl < 17) ? cl : 16;  // clamp garbage rows (discarded at store)
      int rb = (img * 17 + tt) * 68 + hh * 16 + kh * 8;
      int sb = tt * 16 + kh * 8;
      float4 s0 = *(const float4*)(sSin + sb), s1 = *(const float4*)(sSin + sb + 4);
      float4 c0 = *(const float4*)(sCos + sb), c1 = *(const float4*)(sCos + sb + 4);
      float4 qa = *(const float4*)(sQ + rb), qb = *(const float4*)(sQ + rb + 4);
      i32x4 ap;
      ap.x = pack_bf2(qa.x * c0.x - qa.y * s0.x, qa.y * c0.y + qa.x * s0.y);
      ap.y = pack_bf2(qa.z * c0.z - qa.w * s0.z, qa.w * c0.w + qa.z * s0.w);
      ap.z = pack_bf2(qb.x * c1.x - qb.y * s1.x, qb.y * c1.y + qb.x * s1.y);
      ap.w = pack_bf2(qb.z * c1.z - qb.w * s1.z, qb.w * c1.w + qb.z * s1.w);
      float4 ka = *(const float4*)(sK + rb), kb = *(const float4*)(sK + rb + 4);
      i32x4 bp;
      bp.x = pack_bf2(ka.x * c0.x - ka.y * s0.x, ka.y * c0.y + ka.x * s0.y);
      bp.y = pack_bf2(ka.z * c0.z - ka.w * s0.z, ka.w * c0.w + ka.z * s0.w);
      bp.z = pack_bf2(kb.x * c1.x - kb.y * s1.x, kb.y * c1.y + kb.x * s1.y);
      bp.w = pack_bf2(kb.z * c1.z - kb.w * s1.z, kb.w * c1.w + kb.z * s1.w);
      f32x16 acc = {0.f, 0.f, 0.f, 0.f, 0.f, 0.f, 0.f, 0.f,
                    0.f, 0.f, 0.f, 0.f, 0.f, 0.f, 0.f, 0.f};
      acc = MFMA32(as_bf(ap), as_bf(bp), acc, 0, 0, 0);
      if (cl < 17) {  // valid u column; dmask (incl 0.25) zeroes u>t
        int scb = img * 1360 + hh * 340;
        const float* dmb = sDM + hh * 289;
#pragma unroll
        for (int r = 0; r < 16; ++r) {
          int t = (r & 3) + 8 * (r >> 2) + 4 * kh;
          if (t < 17) sSC[scb + t * 20 + cl] = acc[r] * dmb[t * 17 + cl];
        }
      }
    }
    __syncthreads();  // protect all waves' sQ/sK reads before sO (alias) is written

    // ---- AV via MFMA 32x32x16, denominator inline (sequential row sum u=0..16) ----
    {
      int img = w >> 2, hh = w & 3;
      int cl = lane & 31, kh = lane >> 5;
      int tt = (cl < 17) ? cl : 16;
      const float* scb = sSC + img * 1360 + hh * 340;
      const float* rowp = scb + tt * 20;
      float4 p0 = *(const float4*)(rowp);
      float4 p1 = *(const float4*)(rowp + 4);
      float4 p2 = *(const float4*)(rowp + 8);
      float4 p3 = *(const float4*)(rowp + 12);
      float s16v = rowp[16];
      float s = 0.f;
      s += p0.x; s += p0.y; s += p0.z; s += p0.w;
      s += p1.x; s += p1.y; s += p1.z; s += p1.w;
      s += p2.x; s += p2.y; s += p2.z; s += p2.w;
      s += p3.x; s += p3.y; s += p3.z; s += p3.w;
      s += s16v;
      float den = fabsf(s);
      if (den < 1.f) den = 1.f;
      den = 1.f / den;
      float4 av0 = (kh == 0) ? p0 : p2;
      float4 av1 = (kh == 0) ? p1 : p3;
      i32x4 ap;
      ap.x = pack_bf2(av0.x * den, av0.y * den);
      ap.y = pack_bf2(av0.z * den, av0.w * den);
      ap.z = pack_bf2(av1.x * den, av1.y * den);
      ap.w = pack_bf2(av1.z * den, av1.w * den);
      const unsigned short* vcol = sVbT + img * 2560 + (hh * 32 + cl) * 20 + kh * 8;
      const uint2* vq = (const uint2*)vcol;
      uint2 v0 = vq[0], v1 = vq[1];
      i32x4 bp; bp.x = (int)v0.x; bp.y = (int)v0.y; bp.z = (int)v1.x; bp.w = (int)v1.y;
      f32x16 acc = {0.f, 0.f, 0.f, 0.f, 0.f, 0.f, 0.f, 0.f,
                    0.f, 0.f, 0.f, 0.f, 0.f, 0.f, 0.f, 0.f};
      acc = MFMA32(as_bf(ap), as_bf(bp), acc, 0, 0, 0);
      i32x4 a1 = {0, 0, 0, 0}, b1v = {0, 0, 0, 0};
      if (kh == 0) {  // u = 16 tail
        float s16 = s16v * den;
        a1.x = (int)(unsigned)cvt_bf(s16);
        b1v.x = (int)(unsigned)sVbT[img * 2560 + (hh * 32 + cl) * 20 + 16];
      }
      acc = MFMA32(as_bf(a1), as_bf(b1v), acc, 0, 0, 0);
      int cg = hh * 32 + cl;
#pragma unroll
      for (int r = 0; r < 16; ++r) {
        int t = (r & 3) + 8 * (r >> 2) + 4 * kh;
        if (t < 17) sO[(img * 17 + t) * 130 + cg] = acc[r];
      }
    }
    __syncthreads();

    // ---- groupnorm (fused wave-local stats over 4 q-lanes) + silu -> OA frags ----
    for (int s = tid; s < 768; s += 512) {
      int mt = s >> 8, kt = (s >> 6) & 3, la = s & 63;
      int q = la >> 4, m = mt * 16 + (la & 15);
      int cb = kt * 32 + q * 8;
      i32x4 pk = {0, 0, 0, 0};
      if (m < 34) {
        const float2* op = (const float2*)(sO + m * 130 + cb);
        float2 o0 = op[0], o1 = op[1], o2 = op[2], o3 = op[3];
        float s1 = 0.f, s2 = 0.f;
        s1 += o0.x; s2 += o0.x * o0.x; s1 += o0.y; s2 += o0.y * o0.y;
        s1 += o1.x; s2 += o1.x * o1.x; s1 += o1.y; s2 += o1.y * o1.y;
        s1 += o2.x; s2 += o2.x * o2.x; s1 += o2.y; s2 += o2.y * o2.y;
        s1 += o3.x; s2 += o3.x * o3.x; s1 += o3.y; s2 += o3.y * o3.y;
        s1 += __shfl_xor(s1, 16); s2 += __shfl_xor(s2, 16);
        s1 += __shfl_xor(s1, 32); s2 += __shfl_xor(s2, 32);
        float mu = s1 * (1.f / 32.f);
        float var = s2 * (1.f / 32.f) - mu * mu;
        float rr = rsqrtf(var + 1e-5f);
        i32x4 gu = *(const i32x4*)(sGb + m * 136 + cb);
        float ov[8] = {o0.x, o0.y, o1.x, o1.y, o2.x, o2.y, o3.x, o3.y};
        float vv[8];
#pragma unroll
        for (int q2 = 0; q2 < 4; ++q2) {
          unsigned gw = (q2 == 0) ? (unsigned)gu.x : (q2 == 1) ? (unsigned)gu.y
                       : (q2 == 2) ? (unsigned)gu.z : (unsigned)gu.w;
          float2 gv = unpk(gw);
          float on0 = (ov[2 * q2] - mu) * rr;
          float on1 = (ov[2 * q2 + 1] - mu) * rr;
          vv[2 * q2]     = on0 * (gv.x / (1.f + __expf(-gv.x)));
          vv[2 * q2 + 1] = on1 * (gv.y / (1.f + __expf(-gv.y)));
        }
        pk.x = pack_bf2(vv[0], vv[1]); pk.y = pack_bf2(vv[2], vv[3]);
        pk.z = pack_bf2(vv[4], vv[5]); pk.w = pack_bf2(vv[6], vv[7]);
      }
      ((i32x4*)(sm + O_SCA))[s] = pk;
    }
    __syncthreads();

    // ---- Wo MFMA: 12 jobs / 8 waves; += residual ----
    {
      const bf16x8* oaf = (const bf16x8*)(sm + O_SCA);
      const bf16x8* wof = FRB + LB + 3072;
      for (int j = w; j < 12; j += 8) {
        int mt = j >> 2, nt = j & 3;
        f32x4 acc = {0.f, 0.f, 0.f, 0.f};
#pragma unroll
        for (int kt = 0; kt < 4; ++kt)
          acc = MFMA(oaf[(mt * 4 + kt) * 64 + lane], wof[(nt * 4 + kt) * 64 + lane], acc, 0, 0, 0);
        int n = nt * 16 + ln;
#pragma unroll
        for (int i = 0; i < 4; ++i) {
          int m = mt * 16 + lq * 4 + i;
          if (m < 34) sH[m * 66 + n] += acc[i];
        }
      }
    }
    __syncthreads();

    // ---- ln2: fused wave-local stats + A-frag build (8 lanes/row) ----
    if (tid < 320) {
      int m = tid >> 3, sub = tid & 7;
      i32x4 pk = {0, 0, 0, 0};
      if (m < 34) {
        const float2* hp = (const float2*)(sH + m * 66 + sub * 8);
        float2 h0 = hp[0], h1 = hp[1], h2 = hp[2], h3 = hp[3];
        float s1 = 0.f, s2 = 0.f;
        s1 += h0.x; s2 += h0.x * h0.x; s1 += h0.y; s2 += h0.y * h0.y;
        s1 += h1.x; s2 += h1.x * h1.x; s1 += h1.y; s2 += h1.y * h1.y;
        s1 += h2.x; s2 += h2.x * h2.x; s1 += h2.y; s2 += h2.y * h2.y;
        s1 += h3.x; s2 += h3.x * h3.x; s1 += h3.y; s2 += h3.y * h3.y;
        s1 += __shfl_xor(s1, 1); s2 += __shfl_xor(s2, 1);
        s1 += __shfl_xor(s1, 2); s2 += __shfl_xor(s2, 2);
        s1 += __shfl_xor(s1, 4); s2 += __shfl_xor(s2, 4);
        float mu = s1 * (1.f / 64.f);
        float var = s2 * (1.f / 64.f) - mu * mu;
        float rr = rsqrtf(var + 1e-5f);
        int kb = sub * 8;
        float hv[8] = {h0.x, h0.y, h1.x, h1.y, h2.x, h2.y, h3.x, h3.y};
        float vv[8];
#pragma unroll
        for (int t2 = 0; t2 < 8; t2 += 2) {
          float2 sv = ld2<BF16>(ln2s, l * 64 + kb + t2);
          float2 bv = ld2<BF16>(ln2b, l * 64 + kb + t2);
          vv[t2]     = (hv[t2] - mu) * rr * sv.x + bv.x;
          vv[t2 + 1] = (hv[t2 + 1] - mu) * rr * sv.y + bv.y;
        }
        pk.x = pack_bf2(vv[0], vv[1]); pk.y = pack_bf2(vv[2], vv[3]);
        pk.z = pack_bf2(vv[4], vv[5]); pk.w = pack_bf2(vv[6], vv[7]);
      }
      int slot = (m >> 4) * 128 + (sub >> 2) * 64 + (sub & 3) * 16 + (m & 15);
      ((i32x4*)(sm + O_XNF))[slot] = pk;
    }
    __syncthreads();

    // ---- FFN1 via MFMA: 3 jobs (mt), N=12 in one 16-tile, K=64; gelu at store ----
    if (w < 3) {
      const bf16x8* xnf = (const bf16x8*)(sm + O_XNF);
      const bf16x8* w1f = FRB + 35072 + l * 384;
      int mt = w;
      f32x4 acc = {0.f, 0.f, 0.f, 0.f};
#pragma unroll
      for (int kt = 0; kt < 2; ++kt)
        acc = MFMA(xnf[(mt * 2 + kt) * 64 + lane], w1f[kt * 64 + lane], acc, 0, 0, 0);
      if (ln < 12) {
        float b = ld<BF16>(b1, l * 12 + ln);
#pragma unroll
        for (int i = 0; i < 4; ++i) {
          int m = mt * 16 + lq * 4 + i;
          if (m < 34) {
            float a = acc[i] + b;
            float inner = 0.7978845608028654f * (a + 0.044715f * a * a * a);
            float e = __expf(2.f * inner);
            float th = 1.f - 2.f / (e + 1.f);
            sFF[m * 12 + ln] = 0.5f * a * (1.f + th);
          }
        }
      }
    }
    __syncthreads();

    // ---- FFN2 via MFMA: 12 jobs (mt3 x nt4), K=32 (e padded); bias+residual at store ----
    {
      const bf16x8* w2f = FRB + 35072 + l * 384 + 128;
      for (int j = w; j < 12; j += 8) {
        int mt = j >> 2, nt = j & 3;
        i32x4 ap = {0, 0, 0, 0};
        int ma = mt * 16 + ln;
        if (ma < 34) {
          const float* fp = sFF + ma * 12;
          if (lq == 0) {
            ap.x = pack_bf2(fp[0], fp[1]); ap.y = pack_bf2(fp[2], fp[3]);
            ap.z = pack_bf2(fp[4], fp[5]); ap.w = pack_bf2(fp[6], fp[7]);
          } else if (lq == 1) {
            ap.x = pack_bf2(fp[8], fp[9]); ap.y = pack_bf2(fp[10], fp[11]);
          }
        }
        f32x4 acc = {0.f, 0.f, 0.f, 0.f};
        acc = MFMA(as_bf(ap), w2f[nt * 64 + lane], acc, 0, 0, 0);
        int n = nt * 16 + ln;
        float b = ld<BF16>(b2, l * 64 + n);
#pragma unroll
        for (int i = 0; i < 4; ++i) {
          int m = mt * 16 + lq * 4 + i;
          if (m < 34) sH[m * 66 + n] += acc[i] + b;
        }
      }
    }
    __syncthreads();
  }

  // ---- final: lnf (last token each image), neck, head ----
  if (tid < 2) {
    int m = tid * 17 + 16;
    float s1 = 0.f, s2 = 0.f;
    for (int d = 0; d < 64; ++d) {
      float v = sH[m * 66 + d];
      s1 += v; s2 += v * v;
    }
    float mu = s1 * (1.f / 64.f);
    float var = s2 * (1.f / 64.f) - mu * mu;
    sST[tid] = mu;
    sST[2 + tid] = rsqrtf(var + 1e-5f);
  }
  __syncthreads();
  if (tid < 32) {
    int img = tid >> 4, jn = tid & 15;
    int m = img * 17 + 16;
    float mu = sST[img], rr = sST[2 + img];
    float acc = ld<BF16>(neckb, jn);
    for (int d = 0; d < 64; ++d) {
      float yn = (sH[m * 66 + d] - mu) * rr * ld<BF16>(lnfs, d) + ld<BF16>(lnfb, d);
      acc += yn * ld<BF16>(neckw, d * 16 + jn);
    }
    sST[8 + img * 16 + jn] = acc;
  }
  __syncthreads();
  if (tid < 20) {
    int img = tid / 10, o = tid % 10;
    float acc = ld<BF16>(headb, o);
#pragma unroll
    for (int e = 0; e < 16; ++e) acc += sST[8 + img * 16 + e] * ld<BF16>(headw, e * 10 + o);
    if (BF16) {
      ((__hip_bfloat16*)out)[(img0 + img) * 10 + o] = __float2bfloat16(acc);
    } else {
      ((float*)out)[(img0 + img) * 10 + o] = acc;
    }
  }
}

extern "C" void kernel_launch(void* const* d_in, const int* in_sizes, int n_in,
                              void* d_out, int out_size, void* d_ws, size_t ws_size,
                              hipStream_t stream) {
  float* tab = (float*)d_ws;
  unsigned short* frag = (unsigned short*)((char*)d_ws + 8192);

  setup_tables<<<dim3(1), dim3(256), 0, stream>>>(tab, d_in[0]);

  const int prepBlocks = (FRAG_TOT + 255) / 256;
  prep_frags<false><<<dim3(prepBlocks), dim3(256), 0, stream>>>(
      d_in[1], d_in[5], d_in[6], d_in[7], d_in[8], d_in[9], d_in[12], d_in[14], tab, frag);
  prep_frags<true><<<dim3(prepBlocks), dim3(256), 0, stream>>>(
      d_in[1], d_in[5], d_in[6], d_in[7], d_in[8], d_in[9], d_in[12], d_in[14], tab, frag);

  const int B = in_sizes[0] / 3072;
  const int grid = B / 2;

  vit_fused<false><<<dim3(grid), dim3(512), 0, stream>>>(
      d_in[0], d_in[2], d_in[3], d_in[4], d_in[10], d_in[11], d_in[13],
      d_in[15], d_in[16], d_in[17], d_in[18], d_in[19], d_in[20], d_in[21],
      d_in[22], d_in[23], tab, frag, d_out);
  vit_fused<true><<<dim3(grid), dim3(512), 0, stream>>>(
      d_in[0], d_in[2], d_in[3], d_in[4], d_in[10], d_in[11], d_in[13],
      d_in[15], d_in[16], d_in[17], d_in[18], d_in[19], d_in[20], d_in[21],
      d_in[22], d_in[23], tab, frag, d_out);
}

// Round 8
// 762.675 us; speedup vs baseline: 1.6094x; 1.0373x over previous
//
#include <hip/hip_runtime.h>
#include <hip/hip_bf16.h>

#define NLAY 8
#define MFMA __builtin_amdgcn_mfma_f32_16x16x32_bf16
#define MFMA32 __builtin_amdgcn_mfma_f32_32x32x16_bf16

typedef __attribute__((ext_vector_type(8))) short bf16x8;
typedef __attribute__((ext_vector_type(4))) float f32x4;
typedef __attribute__((ext_vector_type(16))) float f32x16;
typedef __attribute__((ext_vector_type(4))) int i32x4;

template <bool BF16>
__device__ __forceinline__ float ld(const void* p, int i) {
  if (BF16) {
    unsigned short u = ((const unsigned short*)p)[i];
    return __uint_as_float(((unsigned)u) << 16);
  }
  return ((const float*)p)[i];
}

template <bool BF16>
__device__ __forceinline__ float2 ld2(const void* p, int i) {  // i even
  float2 r;
  if (BF16) {
    unsigned u = ((const unsigned*)p)[i >> 1];
    r.x = __uint_as_float(u << 16);
    r.y = __uint_as_float(u & 0xffff0000u);
  } else {
    r = ((const float2*)p)[i >> 1];
  }
  return r;
}

__device__ __forceinline__ unsigned pack_bf2(float a, float b) {
  __hip_bfloat16 ha = __float2bfloat16(a), hb = __float2bfloat16(b);
  unsigned short ua, ub;
  __builtin_memcpy(&ua, &ha, 2);
  __builtin_memcpy(&ub, &hb, 2);
  return ((unsigned)ub << 16) | (unsigned)ua;
}

__device__ __forceinline__ unsigned short cvt_bf(float a) {
  __hip_bfloat16 h = __float2bfloat16(a);
  unsigned short us;
  __builtin_memcpy(&us, &h, 2);
  return us;
}

__device__ __forceinline__ float2 unpk(unsigned u) {
  float2 r;
  r.x = __uint_as_float(u << 16);
  r.y = __uint_as_float(u & 0xffff0000u);
  return r;
}

__device__ __forceinline__ bf16x8 as_bf(i32x4 v) {
  bf16x8 r;
  __builtin_memcpy(&r, &v, 16);
  return r;
}

// ws[0..271]=sin, ws[272..543]=cos, ws[544..1699]=dmask, ws[1700]=dtype flag
__global__ void setup_tables(float* __restrict__ ws, const void* __restrict__ x) {
  int tid = threadIdx.x;
  for (int idx = tid; idx < 272; idx += 256) {
    int t = idx >> 4, j = idx & 15;
    float a = powf(10000.f, -(float)(j >> 1) / 7.f);
    float arg = (float)t * a;
    ws[idx] = sinf(arg);
    ws[272 + idx] = cosf(arg);
  }
  for (int row = tid; row < 68; row += 256) {
    int hh = row / 17, t = row % 17;
    float gamma = 1.f - exp2f(-5.f - 4.f * (float)hh / 3.f);
    float sum = 0.f;
    for (int u = 0; u <= t; ++u) sum += powf(gamma, (float)(t - u));
    float rn = rsqrtf(sum);
    for (int u = 0; u < 17; ++u)
      ws[544 + row * 17 + u] = (u <= t) ? powf(gamma, (float)(t - u)) * rn : 0.f;
  }
  if (tid == 0) {
    const unsigned short* u16 = (const unsigned short*)x;
    int sane = 0;
    for (int i = 0; i < 128; ++i) {
      float v = __uint_as_float(((unsigned)u16[2 * i]) << 16);
      float av = fabsf(v);
      if (v == 0.f || (av > 1e-8f && av < 1e4f)) sane++;
    }
    ws[1700] = (sane >= 64) ? 1.f : 0.f;
  }
}

// Pre-swizzle weights into MFMA B-fragment order (bf16), into ws+8192 bytes.
#define FRAG_OLD 280576
#define FRAG_TOT 305152
template <bool BF16>
__global__ void prep_frags(const void* __restrict__ patch_w,
                           const void* __restrict__ Wq, const void* __restrict__ Wk,
                           const void* __restrict__ Wv, const void* __restrict__ Wg,
                           const void* __restrict__ Wo, const void* __restrict__ w1,
                           const void* __restrict__ w2,
                           const float* __restrict__ tab,
                           unsigned short* __restrict__ frag) {
  if ((tab[1700] > 0.5f) != BF16) return;
  int g = blockIdx.x * 256 + threadIdx.x;
  if (g >= FRAG_TOT) return;
  float v;
  if (g < 12288) {  // patch_w: K=192 (kt6), N=64 (nt4)
    int nt = g / 3072, r = g % 3072, kt = r / 512, r2 = r % 512, la = r2 >> 3, j = r2 & 7;
    int n = nt * 16 + (la & 15), k = kt * 32 + (la >> 4) * 8 + j;
    v = ld<BF16>(patch_w, k * 64 + n);
  } else if (g < FRAG_OLD) {
    int gg = g - 12288, l = gg / 33536, o = gg % 33536;
    if (o < 8192) {  // Wq / Wk
      const void* W = (o < 4096) ? Wq : Wk;
      int e = o & 4095;
      int nt = e / 1024, r = e % 1024, kt = r / 512, r2 = r % 512, la = r2 >> 3, j = r2 & 7;
      int n = nt * 16 + (la & 15), k = kt * 32 + (la >> 4) * 8 + j;
      v = ld<BF16>(W, l * 4096 + k * 64 + n);
    } else if (o < 24576) {  // Wv / Wg
      const void* W = (o < 16384) ? Wv : Wg;
      int e = (o - 8192) & 8191;
      int nt = e / 1024, r = e % 1024, kt = r / 512, r2 = r % 512, la = r2 >> 3, j = r2 & 7;
      int n = nt * 16 + (la & 15), k = kt * 32 + (la >> 4) * 8 + j;
      v = ld<BF16>(W, l * 8192 + k * 128 + n);
    } else if (o < 32768) {  // Wo
      int e = o - 24576;
      int nt = e / 2048, r = e % 2048, kt = r / 512, r2 = r % 512, la = r2 >> 3, j = r2 & 7;
      int n = nt * 16 + (la & 15), k = kt * 32 + (la >> 4) * 8 + j;
      v = ld<BF16>(Wo, l * 8192 + k * 64 + n);
    } else {  // legacy w1T (unused)
      int e = o - 32768, eo = e / 64, d = e % 64;
      v = ld<BF16>(w1, l * 768 + d * 12 + eo);
    }
  } else {  // w1 / w2 B-frags
    int gg = g - FRAG_OLD, l = gg / 3072, o = gg % 3072;
    if (o < 1024) {  // w1 B-frag: n=e (pad>=12), k=d, kt 0..1
      int kt = o >> 9, r = o & 511, la = r >> 3, j = r & 7;
      int n = la & 15, k = kt * 32 + (la >> 4) * 8 + j;
      v = (n < 12) ? ld<BF16>(w1, l * 768 + k * 12 + n) : 0.f;
    } else {  // w2 B-frag: n=d (nt 0..3), k=e (pad>=12), K=32
      int e2 = o - 1024;
      int nt = e2 >> 9, r = e2 & 511, la = r >> 3, j = r & 7;
      int n = nt * 16 + (la & 15), k = (la >> 4) * 8 + j;
      v = (k < 12) ? ld<BF16>(w2, (l * 12 + k) * 64 + n) : 0.f;
    }
  }
  __hip_bfloat16 h = __float2bfloat16(v);
  unsigned short us;
  __builtin_memcpy(&us, &h, 2);
  frag[g] = us;
}

// LDS float offsets
#define O_DM   0      // 1156 (dmask * 0.25 folded)
#define O_SIN  1156   // 272
#define O_COS  1428   // 272
#define O_ST   1700   // 512
#define O_H    2212   // 2244: H fp32 34x66
#define O_XNF  4456   // 1536: XN A-frags (ln1 / ln2)
#define O_FF   5992   // 408
#define O_R    6400   // 4624: Q 34x68 + K 34x68 / alias O fp32 34x134 (4556)
#define O_SCA  11024  // 3072: patch A-frags / OA frags
#define O_VG   14096  // 4872: VT bf16 2x128x20 (2560 f) + G bf16 34x136 (2312 f)
#define SM_TOT 18968

template <bool BF16>
__global__ void __launch_bounds__(512, 4)
vit_fused(const void* __restrict__ x, const void* __restrict__ patch_b,
          const void* __restrict__ cls, const void* __restrict__ pos,
          const void* __restrict__ ln1s, const void* __restrict__ ln1b,
          const void* __restrict__ b1, const void* __restrict__ b2,
          const void* __restrict__ ln2s, const void* __restrict__ ln2b,
          const void* __restrict__ lnfs, const void* __restrict__ lnfb,
          const void* __restrict__ neckw, const void* __restrict__ neckb,
          const void* __restrict__ headw, const void* __restrict__ headb,
          const float* __restrict__ tab, const unsigned short* __restrict__ FR,
          void* __restrict__ out) {
  if ((tab[1700] > 0.5f) != BF16) return;

  const int tid = threadIdx.x;
  const int lane = tid & 63, w = tid >> 6;  // w in 0..7
  const int lq = lane >> 4, ln = lane & 15;
  const int img0 = 2 * blockIdx.x;

  __shared__ __align__(16) float sm[SM_TOT];
  float* sDM  = sm + O_DM;
  float* sSin = sm + O_SIN;
  float* sCos = sm + O_COS;
  float* sST  = sm + O_ST;
  float* sH   = sm + O_H;
  float* sFF  = sm + O_FF;
  float* sQ   = sm + O_R;          // 34x68
  float* sK   = sm + O_R + 2312;   // 34x68
  float* sO   = sm + O_R;          // alias, 34x134
  unsigned short* sVbT = (unsigned short*)(sm + O_VG);          // 2 x 128 x 20 (c-major, t inner)
  unsigned short* sGb  = (unsigned short*)(sm + O_VG) + 5120;   // 34x136
  const bf16x8* FRB = (const bf16x8*)FR;

  // ---- stage tables + patch A-frags + cls rows ----
  for (int i = tid; i < 1156; i += 512) sDM[i] = tab[544 + i] * 0.25f;  // K-scale folded
  for (int i = tid; i < 272; i += 512) { sSin[i] = tab[i]; sCos[i] = tab[272 + i]; }
  for (int s = tid; s < 768; s += 512) {  // patch A-frags into O_SCA
    int mt = s / 384, r = s % 384, kt = r / 64, la = r % 64;
    int p = la & 15, q = la >> 4;
    int kb = kt * 32 + q * 8;
    int c = kb >> 6, rem = kb & 63, a = rem >> 3;
    int pi = p >> 2, pj = p & 3;
    int src = (img0 + mt) * 3072 + c * 1024 + (pi * 8 + a) * 32 + pj * 8;
    float v[8];
#pragma unroll
    for (int t2 = 0; t2 < 8; t2 += 2) {
      float2 pv = ld2<BF16>(x, src + t2);
      v[t2] = pv.x; v[t2 + 1] = pv.y;
    }
    i32x4 pk;
    pk.x = pack_bf2(v[0], v[1]); pk.y = pack_bf2(v[2], v[3]);
    pk.z = pack_bf2(v[4], v[5]); pk.w = pack_bf2(v[6], v[7]);
    ((i32x4*)(sm + O_SCA))[s] = pk;
  }
  if (tid < 128) {  // cls token rows
    int img = tid >> 6, n = tid & 63;
    sH[(img * 17) * 66 + n] = ld<BF16>(cls, n) + ld<BF16>(pos, n);
  }
  __syncthreads();

  // ---- patch embed MFMA: 8 jobs = 2mt x 4nt, one per wave ----
  {
    int mt = w >> 2, nt = w & 3;
    f32x4 acc = {0.f, 0.f, 0.f, 0.f};
    const bf16x8* paf = (const bf16x8*)(sm + O_SCA);
#pragma unroll
    for (int kt = 0; kt < 6; ++kt)
      acc = MFMA(paf[(mt * 6 + kt) * 64 + lane], FRB[(nt * 6 + kt) * 64 + lane], acc, 0, 0, 0);
    int n = nt * 16 + ln;
    float pb = ld<BF16>(patch_b, n);
#pragma unroll
    for (int i = 0; i < 4; ++i) {
      int t = 1 + lq * 4 + i;
      sH[(mt * 17 + t) * 66 + n] = acc[i] + pb + ld<BF16>(pos, t * 64 + n);
    }
  }
  __syncthreads();

  for (int l = 0; l < NLAY; ++l) {
    const int LB = 1536 + l * 4192;  // layer base, bf16x8 slots

    // ---- ln1: fused wave-local stats + A-frag build (bank-friendly lane map) ----
    if (tid < 320) {
      int la = tid & 63, wv = tid >> 6;
      int m = wv * 8 + (la & 7);
      int sub = ((la >> 3) & 3) + 4 * (la >> 5);
      i32x4 pk = {0, 0, 0, 0};
      if (m < 34) {
        const float2* hp = (const float2*)(sH + m * 66 + sub * 8);
        float2 h0 = hp[0], h1 = hp[1], h2 = hp[2], h3 = hp[3];
        float s1 = 0.f, s2 = 0.f;
        s1 += h0.x; s2 += h0.x * h0.x; s1 += h0.y; s2 += h0.y * h0.y;
        s1 += h1.x; s2 += h1.x * h1.x; s1 += h1.y; s2 += h1.y * h1.y;
        s1 += h2.x; s2 += h2.x * h2.x; s1 += h2.y; s2 += h2.y * h2.y;
        s1 += h3.x; s2 += h3.x * h3.x; s1 += h3.y; s2 += h3.y * h3.y;
        s1 += __shfl_xor(s1, 8);  s2 += __shfl_xor(s2, 8);
        s1 += __shfl_xor(s1, 16); s2 += __shfl_xor(s2, 16);
        s1 += __shfl_xor(s1, 32); s2 += __shfl_xor(s2, 32);
        float mu = s1 * (1.f / 64.f);
        float var = s2 * (1.f / 64.f) - mu * mu;
        float rr = rsqrtf(var + 1e-5f);
        int kb = sub * 8;
        float hv[8] = {h0.x, h0.y, h1.x, h1.y, h2.x, h2.y, h3.x, h3.y};
        float vv[8];
#pragma unroll
        for (int t2 = 0; t2 < 8; t2 += 2) {
          float2 sv = ld2<BF16>(ln1s, l * 64 + kb + t2);
          float2 bv = ld2<BF16>(ln1b, l * 64 + kb + t2);
          vv[t2]     = (hv[t2] - mu) * rr * sv.x + bv.x;
          vv[t2 + 1] = (hv[t2 + 1] - mu) * rr * sv.y + bv.y;
        }
        pk.x = pack_bf2(vv[0], vv[1]); pk.y = pack_bf2(vv[2], vv[3]);
        pk.z = pack_bf2(vv[4], vv[5]); pk.w = pack_bf2(vv[6], vv[7]);
      }
      int slot = (m >> 4) * 128 + (sub >> 2) * 64 + (sub & 3) * 16 + (m & 15);
      ((i32x4*)(sm + O_XNF))[slot] = pk;
    }
    __syncthreads();

    // ---- QKVG MFMA: 3 phases (QK / V / G) x 3 mt, specialized stores ----
    {
      const bf16x8* xnf = (const bf16x8*)(sm + O_XNF);
      // phase QK: waves 0-3 -> Q, waves 4-7 -> K
      {
        const bf16x8* wf = FRB + LB + ((w < 4) ? 0 : 512);
        float* dst = (w < 4) ? sQ : sK;
        int ntl = w & 3;
        int n = ntl * 16 + ln;
#pragma unroll
        for (int mt = 0; mt < 3; ++mt) {
          f32x4 acc = {0.f, 0.f, 0.f, 0.f};
          acc = MFMA(xnf[(mt * 2) * 64 + lane], wf[(ntl * 2) * 64 + lane], acc, 0, 0, 0);
          acc = MFMA(xnf[(mt * 2 + 1) * 64 + lane], wf[(ntl * 2 + 1) * 64 + lane], acc, 0, 0, 0);
          if (mt < 2) {
            float* p = dst + (mt * 16 + lq * 4) * 68 + n;
            p[0] = acc[0]; p[68] = acc[1]; p[136] = acc[2]; p[204] = acc[3];
          } else if (lq == 0) {
            float* p = dst + 32 * 68 + n;
            p[0] = acc[0]; p[68] = acc[1];
          }
        }
      }
      // phase V: transposed bf16 store, n = w*16+ln in 0..127
      {
        const bf16x8* wf = FRB + LB + 1024;
        int n = w * 16 + ln;
#pragma unroll
        for (int mt = 0; mt < 3; ++mt) {
          f32x4 acc = {0.f, 0.f, 0.f, 0.f};
          acc = MFMA(xnf[(mt * 2) * 64 + lane], wf[(w * 2) * 64 + lane], acc, 0, 0, 0);
          acc = MFMA(xnf[(mt * 2 + 1) * 64 + lane], wf[(w * 2 + 1) * 64 + lane], acc, 0, 0, 0);
          if (mt == 0) {  // img0, t = lq*4..+3: one b64 store
            uint2 uv;
            uv.x = pack_bf2(acc[0], acc[1]);
            uv.y = pack_bf2(acc[2], acc[3]);
            *(uint2*)(sVbT + n * 20 + lq * 4) = uv;
          } else if (mt == 1) {  // straddles image boundary
#pragma unroll
            for (int i = 0; i < 4; ++i) {
              int m = 16 + lq * 4 + i;
              int img = (m >= 17), t = m - img * 17;
              sVbT[img * 2560 + n * 20 + t] = cvt_bf(acc[i]);
            }
          } else if (lq == 0) {  // m=32,33 -> img1 t=15,16
            sVbT[2560 + n * 20 + 15] = cvt_bf(acc[0]);
            sVbT[2560 + n * 20 + 16] = cvt_bf(acc[1]);
          }
        }
      }
      // phase G: row-major bf16, n = w*16+ln in 0..127
      {
        const bf16x8* wf = FRB + LB + 2048;
        int n = w * 16 + ln;
#pragma unroll
        for (int mt = 0; mt < 3; ++mt) {
          f32x4 acc = {0.f, 0.f, 0.f, 0.f};
          acc = MFMA(xnf[(mt * 2) * 64 + lane], wf[(w * 2) * 64 + lane], acc, 0, 0, 0);
          acc = MFMA(xnf[(mt * 2 + 1) * 64 + lane], wf[(w * 2 + 1) * 64 + lane], acc, 0, 0, 0);
          if (mt < 2) {
            unsigned short* p = sGb + (mt * 16 + lq * 4) * 136 + n;
            p[0] = cvt_bf(acc[0]); p[136] = cvt_bf(acc[1]);
            p[272] = cvt_bf(acc[2]); p[408] = cvt_bf(acc[3]);
          } else if (lq == 0) {
            sGb[32 * 136 + n] = cvt_bf(acc[0]);
            sGb[33 * 136 + n] = cvt_bf(acc[1]);
          }
        }
      }
    }
    __syncthreads();

    // ---- fused scores+AV: swapped MFMA32 keeps P in registers ----
    {
      int img = w >> 2, hh = w & 3;
      int cl = lane & 31, kh = lane >> 5;
      int tt = (cl < 17) ? cl : 16;  // clamp garbage rows (discarded at store)
      int rb = (img * 17 + tt) * 68 + hh * 16 + kh * 8;
      int sb = tt * 16 + kh * 8;
      float4 s0 = *(const float4*)(sSin + sb), s1 = *(const float4*)(sSin + sb + 4);
      float4 c0 = *(const float4*)(sCos + sb), c1 = *(const float4*)(sCos + sb + 4);
      float4 qa = *(const float4*)(sQ + rb), qb = *(const float4*)(sQ + rb + 4);
      i32x4 ap;
      ap.x = pack_bf2(qa.x * c0.x - qa.y * s0.x, qa.y * c0.y + qa.x * s0.y);
      ap.y = pack_bf2(qa.z * c0.z - qa.w * s0.z, qa.w * c0.w + qa.z * s0.w);
      ap.z = pack_bf2(qb.x * c1.x - qb.y * s1.x, qb.y * c1.y + qb.x * s1.y);
      ap.w = pack_bf2(qb.z * c1.z - qb.w * s1.z, qb.w * c1.w + qb.z * s1.w);
      float4 ka = *(const float4*)(sK + rb), kb = *(const float4*)(sK + rb + 4);
      i32x4 bp;
      bp.x = pack_bf2(ka.x * c0.x - ka.y * s0.x, ka.y * c0.y + ka.x * s0.y);
      bp.y = pack_bf2(ka.z * c0.z - ka.w * s0.z, ka.w * c0.w + ka.z * s0.w);
      bp.z = pack_bf2(kb.x * c1.x - kb.y * s1.x, kb.y * c1.y + kb.x * s1.y);
      bp.w = pack_bf2(kb.z * c1.z - kb.w * s1.z, kb.w * c1.w + kb.z * s1.w);
      // V B-frag + tail (sVbT is stable since QKVG barrier)
      const unsigned short* vcol = sVbT + img * 2560 + (hh * 32 + cl) * 20 + kh * 8;
      uint2 v0 = ((const uint2*)vcol)[0], v1 = ((const uint2*)vcol)[1];
      i32x4 bpv; bpv.x = (int)v0.x; bpv.y = (int)v0.y; bpv.z = (int)v1.x; bpv.w = (int)v1.y;
      unsigned short v16 = sVbT[img * 2560 + (hh * 32 + cl) * 20 + 16];
      __syncthreads();  // all sQ/sK reads done; sO (alias) writes follow

      f32x16 acc = {0.f, 0.f, 0.f, 0.f, 0.f, 0.f, 0.f, 0.f,
                    0.f, 0.f, 0.f, 0.f, 0.f, 0.f, 0.f, 0.f};
      acc = MFMA32(as_bf(bp), as_bf(ap), acc, 0, 0, 0);  // C[u][t]: lane cl holds row t=cl
      // dmask (incl 0.25) + causal; u=(r&3)+8*(r>>2)+4*kh
      const float* dmr = sDM + hh * 289 + tt * 17;
      float p[16];
#pragma unroll
      for (int r = 0; r < 16; ++r) {
        int u = (r & 3) + 8 * (r >> 2) + 4 * kh;
        p[r] = (u <= 16) ? acc[r] * dmr[u] : 0.f;
      }
      // denominator: own half + partner half
      float own = 0.f;
#pragma unroll
      for (int r = 0; r < 16; ++r) own += p[r];
      float den = fabsf(own + __shfl_xor(own, 32));
      if (den < 1.f) den = 1.f;
      den = 1.f / den;
      // exchange halves for AV A-frag: kh0 needs u4..7 (partner p0..3), kh1 needs u8..11 (partner p4..7)
      float ex[4];
#pragma unroll
      for (int j = 0; j < 4; ++j)
        ex[j] = __shfl_xor((kh == 0) ? p[4 + j] : p[j], 32);
      float pd[8];
#pragma unroll
      for (int j = 0; j < 4; ++j) {
        pd[j]     = ((kh == 0) ? p[j]  : ex[j])     * den;  // kh0: u=j   ; kh1: u=8+j
        pd[4 + j] = ((kh == 0) ? ex[j] : p[4 + j])  * den;  // kh0: u=4+j ; kh1: u=12+j
      }
      i32x4 apv;
      apv.x = pack_bf2(pd[0], pd[1]); apv.y = pack_bf2(pd[2], pd[3]);
      apv.z = pack_bf2(pd[4], pd[5]); apv.w = pack_bf2(pd[6], pd[7]);
      f32x16 ao = {0.f, 0.f, 0.f, 0.f, 0.f, 0.f, 0.f, 0.f,
                   0.f, 0.f, 0.f, 0.f, 0.f, 0.f, 0.f, 0.f};
      ao = MFMA32(as_bf(apv), as_bf(bpv), ao, 0, 0, 0);
      i32x4 a1 = {0, 0, 0, 0}, b1v = {0, 0, 0, 0};
      if (kh == 0) {  // u=16 tail: p[8] holds u=16 for kh=0
        a1.x = (int)(unsigned)cvt_bf(p[8] * den);
        b1v.x = (int)(unsigned)v16;
      }
      ao = MFMA32(as_bf(a1), as_bf(b1v), ao, 0, 0, 0);
      int cg = hh * 32 + cl;
#pragma unroll
      for (int r = 0; r < 16; ++r) {
        int t = (r & 3) + 8 * (r >> 2) + 4 * kh;
        if (t < 17) sO[(img * 17 + t) * 134 + cg] = ao[r];
      }
    }
    __syncthreads();

    // ---- groupnorm (fused wave-local stats over 4 q-lanes) + silu -> OA frags ----
    for (int s = tid; s < 768; s += 512) {
      int mt = s >> 8, kt = (s >> 6) & 3, la = s & 63;
      int q = la >> 4, m = mt * 16 + (la & 15);
      int cb = kt * 32 + q * 8;
      i32x4 pk = {0, 0, 0, 0};
      if (m < 34) {
        const float2* op = (const float2*)(sO + m * 134 + cb);
        float2 o0 = op[0], o1 = op[1], o2 = op[2], o3 = op[3];
        float s1 = 0.f, s2 = 0.f;
        s1 += o0.x; s2 += o0.x * o0.x; s1 += o0.y; s2 += o0.y * o0.y;
        s1 += o1.x; s2 += o1.x * o1.x; s1 += o1.y; s2 += o1.y * o1.y;
        s1 += o2.x; s2 += o2.x * o2.x; s1 += o2.y; s2 += o2.y * o2.y;
        s1 += o3.x; s2 += o3.x * o3.x; s1 += o3.y; s2 += o3.y * o3.y;
        s1 += __shfl_xor(s1, 16); s2 += __shfl_xor(s2, 16);
        s1 += __shfl_xor(s1, 32); s2 += __shfl_xor(s2, 32);
        float mu = s1 * (1.f / 32.f);
        float var = s2 * (1.f / 32.f) - mu * mu;
        float rr = rsqrtf(var + 1e-5f);
        i32x4 gu = *(const i32x4*)(sGb + m * 136 + cb);
        float ov[8] = {o0.x, o0.y, o1.x, o1.y, o2.x, o2.y, o3.x, o3.y};
        float vv[8];
#pragma unroll
        for (int q2 = 0; q2 < 4; ++q2) {
          unsigned gw = (q2 == 0) ? (unsigned)gu.x : (q2 == 1) ? (unsigned)gu.y
                       : (q2 == 2) ? (unsigned)gu.z : (unsigned)gu.w;
          float2 gv = unpk(gw);
          float on0 = (ov[2 * q2] - mu) * rr;
          float on1 = (ov[2 * q2 + 1] - mu) * rr;
          vv[2 * q2]     = on0 * (gv.x / (1.f + __expf(-gv.x)));
          vv[2 * q2 + 1] = on1 * (gv.y / (1.f + __expf(-gv.y)));
        }
        pk.x = pack_bf2(vv[0], vv[1]); pk.y = pack_bf2(vv[2], vv[3]);
        pk.z = pack_bf2(vv[4], vv[5]); pk.w = pack_bf2(vv[6], vv[7]);
      }
      ((i32x4*)(sm + O_SCA))[s] = pk;
    }
    __syncthreads();

    // ---- Wo MFMA: 12 jobs / 8 waves; += residual ----
    {
      const bf16x8* oaf = (const bf16x8*)(sm + O_SCA);
      const bf16x8* wof = FRB + LB + 3072;
      for (int j = w; j < 12; j += 8) {
        int mt = j >> 2, nt = j & 3;
        f32x4 acc = {0.f, 0.f, 0.f, 0.f};
#pragma unroll
        for (int kt = 0; kt < 4; ++kt)
          acc = MFMA(oaf[(mt * 4 + kt) * 64 + lane], wof[(nt * 4 + kt) * 64 + lane], acc, 0, 0, 0);
        int n = nt * 16 + ln;
#pragma unroll
        for (int i = 0; i < 4; ++i) {
          int m = mt * 16 + lq * 4 + i;
          if (m < 34) sH[m * 66 + n] += acc[i];
        }
      }
    }
    __syncthreads();

    // ---- ln2: fused wave-local stats + A-frag build (bank-friendly lane map) ----
    if (tid < 320) {
      int la = tid & 63, wv = tid >> 6;
      int m = wv * 8 + (la & 7);
      int sub = ((la >> 3) & 3) + 4 * (la >> 5);
      i32x4 pk = {0, 0, 0, 0};
      if (m < 34) {
        const float2* hp = (const float2*)(sH + m * 66 + sub * 8);
        float2 h0 = hp[0], h1 = hp[1], h2 = hp[2], h3 = hp[3];
        float s1 = 0.f, s2 = 0.f;
        s1 += h0.x; s2 += h0.x * h0.x; s1 += h0.y; s2 += h0.y * h0.y;
        s1 += h1.x; s2 += h1.x * h1.x; s1 += h1.y; s2 += h1.y * h1.y;
        s1 += h2.x; s2 += h2.x * h2.x; s1 += h2.y; s2 += h2.y * h2.y;
        s1 += h3.x; s2 += h3.x * h3.x; s1 += h3.y; s2 += h3.y * h3.y;
        s1 += __shfl_xor(s1, 8);  s2 += __shfl_xor(s2, 8);
        s1 += __shfl_xor(s1, 16); s2 += __shfl_xor(s2, 16);
        s1 += __shfl_xor(s1, 32); s2 += __shfl_xor(s2, 32);
        float mu = s1 * (1.f / 64.f);
        float var = s2 * (1.f / 64.f) - mu * mu;
        float rr = rsqrtf(var + 1e-5f);
        int kb = sub * 8;
        float hv[8] = {h0.x, h0.y, h1.x, h1.y, h2.x, h2.y, h3.x, h3.y};
        float vv[8];
#pragma unroll
        for (int t2 = 0; t2 < 8; t2 += 2) {
          float2 sv = ld2<BF16>(ln2s, l * 64 + kb + t2);
          float2 bv = ld2<BF16>(ln2b, l * 64 + kb + t2);
          vv[t2]     = (hv[t2] - mu) * rr * sv.x + bv.x;
          vv[t2 + 1] = (hv[t2 + 1] - mu) * rr * sv.y + bv.y;
        }
        pk.x = pack_bf2(vv[0], vv[1]); pk.y = pack_bf2(vv[2], vv[3]);
        pk.z = pack_bf2(vv[4], vv[5]); pk.w = pack_bf2(vv[6], vv[7]);
      }
      int slot = (m >> 4) * 128 + (sub >> 2) * 64 + (sub & 3) * 16 + (m & 15);
      ((i32x4*)(sm + O_XNF))[slot] = pk;
    }
    __syncthreads();

    // ---- FFN1 via MFMA: 3 jobs (mt), N=12 in one 16-tile, K=64; gelu at store ----
    if (w < 3) {
      const bf16x8* xnf = (const bf16x8*)(sm + O_XNF);
      const bf16x8* w1f = FRB + 35072 + l * 384;
      int mt = w;
      f32x4 acc = {0.f, 0.f, 0.f, 0.f};
#pragma unroll
      for (int kt = 0; kt < 2; ++kt)
        acc = MFMA(xnf[(mt * 2 + kt) * 64 + lane], w1f[kt * 64 + lane], acc, 0, 0, 0);
      if (ln < 12) {
        float b = ld<BF16>(b1, l * 12 + ln);
#pragma unroll
        for (int i = 0; i < 4; ++i) {
          int m = mt * 16 + lq * 4 + i;
          if (m < 34) {
            float a = acc[i] + b;
            float inner = 0.7978845608028654f * (a + 0.044715f * a * a * a);
            float e = __expf(2.f * inner);
            float th = 1.f - 2.f / (e + 1.f);
            sFF[m * 12 + ln] = 0.5f * a * (1.f + th);
          }
        }
      }
    }
    __syncthreads();

    // ---- FFN2 via MFMA: 12 jobs (mt3 x nt4), K=32 (e padded); bias+residual at store ----
    {
      const bf16x8* w2f = FRB + 35072 + l * 384 + 128;
      for (int j = w; j < 12; j += 8) {
        int mt = j >> 2, nt = j & 3;
        i32x4 ap = {0, 0, 0, 0};
        int ma = mt * 16 + ln;
        if (ma < 34) {
          const float* fp = sFF + ma * 12;
          if (lq == 0) {
            ap.x = pack_bf2(fp[0], fp[1]); ap.y = pack_bf2(fp[2], fp[3]);
            ap.z = pack_bf2(fp[4], fp[5]); ap.w = pack_bf2(fp[6], fp[7]);
          } else if (lq == 1) {
            ap.x = pack_bf2(fp[8], fp[9]); ap.y = pack_bf2(fp[10], fp[11]);
          }
        }
        f32x4 acc = {0.f, 0.f, 0.f, 0.f};
        acc = MFMA(as_bf(ap), w2f[nt * 64 + lane], acc, 0, 0, 0);
        int n = nt * 16 + ln;
        float b = ld<BF16>(b2, l * 64 + n);
#pragma unroll
        for (int i = 0; i < 4; ++i) {
          int m = mt * 16 + lq * 4 + i;
          if (m < 34) sH[m * 66 + n] += acc[i] + b;
        }
      }
    }
    __syncthreads();
  }

  // ---- final: lnf (last token each image), neck, head ----
  if (tid < 2) {
    int m = tid * 17 + 16;
    float s1 = 0.f, s2 = 0.f;
    for (int d = 0; d < 64; ++d) {
      float v = sH[m * 66 + d];
      s1 += v; s2 += v * v;
    }
    float mu = s1 * (1.f / 64.f);
    float var = s2 * (1.f / 64.f) - mu * mu;
    sST[tid] = mu;
    sST[2 + tid] = rsqrtf(var + 1e-5f);
  }
  __syncthreads();
  if (tid < 32) {
    int img = tid >> 4, jn = tid & 15;
    int m = img * 17 + 16;
    float mu = sST[img], rr = sST[2 + img];
    float acc = ld<BF16>(neckb, jn);
    for (int d = 0; d < 64; ++d) {
      float yn = (sH[m * 66 + d] - mu) * rr * ld<BF16>(lnfs, d) + ld<BF16>(lnfb, d);
      acc += yn * ld<BF16>(neckw, d * 16 + jn);
    }
    sST[8 + img * 16 + jn] = acc;
  }
  __syncthreads();
  if (tid < 20) {
    int img = tid / 10, o = tid % 10;
    float acc = ld<BF16>(headb, o);
#pragma unroll
    for (int e = 0; e < 16; ++e) acc += sST[8 + img * 16 + e] * ld<BF16>(headw, e * 10 + o);
    if (BF16) {
      ((__hip_bfloat16*)out)[(img0 + img) * 10 + o] = __float2bfloat16(acc);
    } else {
      ((float*)out)[(img0 + img) * 10 + o] = acc;
    }
  }
}

extern "C" void kernel_launch(void* const* d_in, const int* in_sizes, int n_in,
                              void* d_out, int out_size, void* d_ws, size_t ws_size,
                              hipStream_t stream) {
  float* tab = (float*)d_ws;
  unsigned short* frag = (unsigned short*)((char*)d_ws + 8192);

  setup_tables<<<dim3(1), dim3(256), 0, stream>>>(tab, d_in[0]);

  const int prepBlocks = (FRAG_TOT + 255) / 256;
  prep_frags<false><<<dim3(prepBlocks), dim3(256), 0, stream>>>(
      d_in[1], d_in[5], d_in[6], d_in[7], d_in[8], d_in[9], d_in[12], d_in[14], tab, frag);
  prep_frags<true><<<dim3(prepBlocks), dim3(256), 0, stream>>>(
      d_in[1], d_in[5], d_in[6], d_in[7], d_in[8], d_in[9], d_in[12], d_in[14], tab, frag);

  const int B = in_sizes[0] / 3072;
  const int grid = B / 2;

  vit_fused<false><<<dim3(grid), dim3(512), 0, stream>>>(
      d_in[0], d_in[2], d_in[3], d_in[4], d_in[10], d_in[11], d_in[13],
      d_in[15], d_in[16], d_in[17], d_in[18], d_in[19], d_in[20], d_in[21],
      d_in[22], d_in[23], tab, frag, d_out);
  vit_fused<true><<<dim3(grid), dim3(512), 0, stream>>>(
      d_in[0], d_in[2], d_in[3], d_in[4], d_in[10], d_in[11], d_in[13],
      d_in[15], d_in[16], d_in[17], d_in[18], d_in[19], d_in[20], d_in[21],
      d_in[22], d_in[23], tab, frag, d_out);
}

// Round 9
// 727.322 us; speedup vs baseline: 1.6876x; 1.0486x over previous
//
#include <hip/hip_runtime.h>
#include <hip/hip_bf16.h>

#define NLAY 8
#define MFMA __builtin_amdgcn_mfma_f32_16x16x32_bf16
#define MFMA32 __builtin_amdgcn_mfma_f32_32x32x16_bf16

typedef __attribute__((ext_vector_type(8))) short bf16x8;
typedef __attribute__((ext_vector_type(4))) float f32x4;
typedef __attribute__((ext_vector_type(16))) float f32x16;
typedef __attribute__((ext_vector_type(4))) int i32x4;

template <bool BF16>
__device__ __forceinline__ float ld(const void* p, int i) {
  if (BF16) {
    unsigned short u = ((const unsigned short*)p)[i];
    return __uint_as_float(((unsigned)u) << 16);
  }
  return ((const float*)p)[i];
}

template <bool BF16>
__device__ __forceinline__ float2 ld2(const void* p, int i) {  // i even
  float2 r;
  if (BF16) {
    unsigned u = ((const unsigned*)p)[i >> 1];
    r.x = __uint_as_float(u << 16);
    r.y = __uint_as_float(u & 0xffff0000u);
  } else {
    r = ((const float2*)p)[i >> 1];
  }
  return r;
}

__device__ __forceinline__ unsigned pack_bf2(float a, float b) {
  __hip_bfloat16 ha = __float2bfloat16(a), hb = __float2bfloat16(b);
  unsigned short ua, ub;
  __builtin_memcpy(&ua, &ha, 2);
  __builtin_memcpy(&ub, &hb, 2);
  return ((unsigned)ub << 16) | (unsigned)ua;
}

__device__ __forceinline__ unsigned short cvt_bf(float a) {
  __hip_bfloat16 h = __float2bfloat16(a);
  unsigned short us;
  __builtin_memcpy(&us, &h, 2);
  return us;
}

__device__ __forceinline__ float2 unpk(unsigned u) {
  float2 r;
  r.x = __uint_as_float(u << 16);
  r.y = __uint_as_float(u & 0xffff0000u);
  return r;
}

__device__ __forceinline__ bf16x8 as_bf(i32x4 v) {
  bf16x8 r;
  __builtin_memcpy(&r, &v, 16);
  return r;
}

// 8 consecutive values starting at element i (i % 8 == 0, 16B-aligned)
template <bool BF16>
__device__ __forceinline__ void ld8v(const void* p, int i, float* v) {
  if (BF16) {
    i32x4 u = *(const i32x4*)((const unsigned short*)p + i);
    float2 a = unpk((unsigned)u.x); v[0] = a.x; v[1] = a.y;
    float2 b = unpk((unsigned)u.y); v[2] = b.x; v[3] = b.y;
    float2 c = unpk((unsigned)u.z); v[4] = c.x; v[5] = c.y;
    float2 d = unpk((unsigned)u.w); v[6] = d.x; v[7] = d.y;
  } else {
    float4 a = *(const float4*)((const float*)p + i);
    float4 b = *(const float4*)((const float*)p + i + 4);
    v[0] = a.x; v[1] = a.y; v[2] = a.z; v[3] = a.w;
    v[4] = b.x; v[5] = b.y; v[6] = b.z; v[7] = b.w;
  }
}

// ws[0..271]=sin, ws[272..543]=cos, ws[544..1699]=dmask, ws[1700]=dtype flag
__global__ void setup_tables(float* __restrict__ ws, const void* __restrict__ x) {
  int tid = threadIdx.x;
  for (int idx = tid; idx < 272; idx += 256) {
    int t = idx >> 4, j = idx & 15;
    float a = powf(10000.f, -(float)(j >> 1) / 7.f);
    float arg = (float)t * a;
    ws[idx] = sinf(arg);
    ws[272 + idx] = cosf(arg);
  }
  for (int row = tid; row < 68; row += 256) {
    int hh = row / 17, t = row % 17;
    float gamma = 1.f - exp2f(-5.f - 4.f * (float)hh / 3.f);
    float sum = 0.f;
    for (int u = 0; u <= t; ++u) sum += powf(gamma, (float)(t - u));
    float rn = rsqrtf(sum);
    for (int u = 0; u < 17; ++u)
      ws[544 + row * 17 + u] = (u <= t) ? powf(gamma, (float)(t - u)) * rn : 0.f;
  }
  if (tid == 0) {
    const unsigned short* u16 = (const unsigned short*)x;
    int sane = 0;
    for (int i = 0; i < 128; ++i) {
      float v = __uint_as_float(((unsigned)u16[2 * i]) << 16);
      float av = fabsf(v);
      if (v == 0.f || (av > 1e-8f && av < 1e4f)) sane++;
    }
    ws[1700] = (sane >= 64) ? 1.f : 0.f;
  }
}

// Pre-swizzle weights into MFMA B-fragment order (bf16), into ws+8192 bytes.
#define FRAG_OLD 280576
#define FRAG_TOT 305152
template <bool BF16>
__global__ void prep_frags(const void* __restrict__ patch_w,
                           const void* __restrict__ Wq, const void* __restrict__ Wk,
                           const void* __restrict__ Wv, const void* __restrict__ Wg,
                           const void* __restrict__ Wo, const void* __restrict__ w1,
                           const void* __restrict__ w2,
                           const float* __restrict__ tab,
                           unsigned short* __restrict__ frag) {
  if ((tab[1700] > 0.5f) != BF16) return;
  int g = blockIdx.x * 256 + threadIdx.x;
  if (g >= FRAG_TOT) return;
  float v;
  if (g < 12288) {  // patch_w: K=192 (kt6), N=64 (nt4)
    int nt = g / 3072, r = g % 3072, kt = r / 512, r2 = r % 512, la = r2 >> 3, j = r2 & 7;
    int n = nt * 16 + (la & 15), k = kt * 32 + (la >> 4) * 8 + j;
    v = ld<BF16>(patch_w, k * 64 + n);
  } else if (g < FRAG_OLD) {
    int gg = g - 12288, l = gg / 33536, o = gg % 33536;
    if (o < 8192) {  // Wq / Wk
      const void* W = (o < 4096) ? Wq : Wk;
      int e = o & 4095;
      int nt = e / 1024, r = e % 1024, kt = r / 512, r2 = r % 512, la = r2 >> 3, j = r2 & 7;
      int n = nt * 16 + (la & 15), k = kt * 32 + (la >> 4) * 8 + j;
      v = ld<BF16>(W, l * 4096 + k * 64 + n);
    } else if (o < 24576) {  // Wv / Wg
      const void* W = (o < 16384) ? Wv : Wg;
      int e = (o - 8192) & 8191;
      int nt = e / 1024, r = e % 1024, kt = r / 512, r2 = r % 512, la = r2 >> 3, j = r2 & 7;
      int n = nt * 16 + (la & 15), k = kt * 32 + (la >> 4) * 8 + j;
      v = ld<BF16>(W, l * 8192 + k * 128 + n);
    } else if (o < 32768) {  // Wo
      int e = o - 24576;
      int nt = e / 2048, r = e % 2048, kt = r / 512, r2 = r % 512, la = r2 >> 3, j = r2 & 7;
      int n = nt * 16 + (la & 15), k = kt * 32 + (la >> 4) * 8 + j;
      v = ld<BF16>(Wo, l * 8192 + k * 64 + n);
    } else {  // legacy w1T (unused)
      int e = o - 32768, eo = e / 64, d = e % 64;
      v = ld<BF16>(w1, l * 768 + d * 12 + eo);
    }
  } else {  // w1 / w2 B-frags
    int gg = g - FRAG_OLD, l = gg / 3072, o = gg % 3072;
    if (o < 1024) {  // w1 B-frag: n=e (pad>=12), k=d, kt 0..1
      int kt = o >> 9, r = o & 511, la = r >> 3, j = r & 7;
      int n = la & 15, k = kt * 32 + (la >> 4) * 8 + j;
      v = (n < 12) ? ld<BF16>(w1, l * 768 + k * 12 + n) : 0.f;
    } else {  // w2 B-frag: n=d (nt 0..3), k=e (pad>=12), K=32
      int e2 = o - 1024;
      int nt = e2 >> 9, r = e2 & 511, la = r >> 3, j = r & 7;
      int n = nt * 16 + (la & 15), k = (la >> 4) * 8 + j;
      v = (k < 12) ? ld<BF16>(w2, (l * 12 + k) * 64 + n) : 0.f;
    }
  }
  __hip_bfloat16 h = __float2bfloat16(v);
  unsigned short us;
  __builtin_memcpy(&us, &h, 2);
  frag[g] = us;
}

// LDS float offsets
#define O_DM   0      // 1156 (dmask * 0.25 folded)
#define O_SIN  1156   // 272
#define O_COS  1428   // 272
#define O_ST   1700   // 512
#define O_H    2212   // 2244: H fp32 34x66
#define O_XNF  4456   // 1536: XN A-frags (ln1 / ln2)
#define O_FF   5992   // 408
#define O_R    6400   // 4624: Qb bf16 34x68 (1156f) + Kb bf16 34x68 / alias O fp32 34x134 (4556)
#define O_SCA  11024  // 3072: patch A-frags / OA frags
#define O_VG   14096  // 4872: VT bf16 2x128x20 (2560 f) + G bf16 34x136 (2312 f)
#define SM_TOT 18968

template <bool BF16>
__global__ void __launch_bounds__(512, 4)
vit_fused(const void* __restrict__ x, const void* __restrict__ patch_b,
          const void* __restrict__ cls, const void* __restrict__ pos,
          const void* __restrict__ ln1s, const void* __restrict__ ln1b,
          const void* __restrict__ b1, const void* __restrict__ b2,
          const void* __restrict__ ln2s, const void* __restrict__ ln2b,
          const void* __restrict__ lnfs, const void* __restrict__ lnfb,
          const void* __restrict__ neckw, const void* __restrict__ neckb,
          const void* __restrict__ headw, const void* __restrict__ headb,
          const float* __restrict__ tab, const unsigned short* __restrict__ FR,
          void* __restrict__ out) {
  if ((tab[1700] > 0.5f) != BF16) return;

  const int tid = threadIdx.x;
  const int lane = tid & 63, w = tid >> 6;  // w in 0..7
  const int lq = lane >> 4, ln = lane & 15;
  const int img0 = 2 * blockIdx.x;

  __shared__ __align__(16) float sm[SM_TOT];
  float* sDM  = sm + O_DM;
  float* sSin = sm + O_SIN;
  float* sCos = sm + O_COS;
  float* sST  = sm + O_ST;
  float* sH   = sm + O_H;
  float* sFF  = sm + O_FF;
  unsigned short* sQb = (unsigned short*)(sm + O_R);          // 34x68 bf16, rotated Q
  unsigned short* sKb = ((unsigned short*)(sm + O_R)) + 2312; // 34x68 bf16, rotated K
  float* sO   = sm + O_R;          // alias, 34x134
  unsigned short* sVbT = (unsigned short*)(sm + O_VG);          // 2 x 128 x 20 (c-major, t inner)
  unsigned short* sGb  = (unsigned short*)(sm + O_VG) + 5120;   // 34x136
  const bf16x8* FRB = (const bf16x8*)FR;

  // ---- stage tables + patch A-frags + cls rows ----
  for (int i = tid; i < 1156; i += 512) sDM[i] = tab[544 + i] * 0.25f;  // K-scale folded
  for (int i = tid; i < 272; i += 512) { sSin[i] = tab[i]; sCos[i] = tab[272 + i]; }
  for (int s = tid; s < 768; s += 512) {  // patch A-frags into O_SCA
    int mt = s / 384, r = s % 384, kt = r / 64, la = r % 64;
    int p = la & 15, q = la >> 4;
    int kb = kt * 32 + q * 8;
    int c = kb >> 6, rem = kb & 63, a = rem >> 3;
    int pi = p >> 2, pj = p & 3;
    int src = (img0 + mt) * 3072 + c * 1024 + (pi * 8 + a) * 32 + pj * 8;
    float v[8];
#pragma unroll
    for (int t2 = 0; t2 < 8; t2 += 2) {
      float2 pv = ld2<BF16>(x, src + t2);
      v[t2] = pv.x; v[t2 + 1] = pv.y;
    }
    i32x4 pk;
    pk.x = pack_bf2(v[0], v[1]); pk.y = pack_bf2(v[2], v[3]);
    pk.z = pack_bf2(v[4], v[5]); pk.w = pack_bf2(v[6], v[7]);
    ((i32x4*)(sm + O_SCA))[s] = pk;
  }
  if (tid < 128) {  // cls token rows
    int img = tid >> 6, n = tid & 63;
    sH[(img * 17) * 66 + n] = ld<BF16>(cls, n) + ld<BF16>(pos, n);
  }
  __syncthreads();

  // ---- patch embed MFMA: 8 jobs = 2mt x 4nt, one per wave ----
  {
    int mt = w >> 2, nt = w & 3;
    f32x4 acc = {0.f, 0.f, 0.f, 0.f};
    const bf16x8* paf = (const bf16x8*)(sm + O_SCA);
#pragma unroll
    for (int kt = 0; kt < 6; ++kt)
      acc = MFMA(paf[(mt * 6 + kt) * 64 + lane], FRB[(nt * 6 + kt) * 64 + lane], acc, 0, 0, 0);
    int n = nt * 16 + ln;
    float pb = ld<BF16>(patch_b, n);
#pragma unroll
    for (int i = 0; i < 4; ++i) {
      int t = 1 + lq * 4 + i;
      sH[(mt * 17 + t) * 66 + n] = acc[i] + pb + ld<BF16>(pos, t * 64 + n);
    }
  }
  __syncthreads();

  for (int l = 0; l < NLAY; ++l) {
    const int LB = 1536 + l * 4192;  // layer base, bf16x8 slots

    // ---- ln1: fused wave-local stats + A-frag build (bank-friendly lane map) ----
    if (tid < 320) {
      int la = tid & 63, wv = tid >> 6;
      int m = wv * 8 + (la & 7);
      int sub = ((la >> 3) & 3) + 4 * (la >> 5);
      i32x4 pk = {0, 0, 0, 0};
      if (m < 34) {
        const float2* hp = (const float2*)(sH + m * 66 + sub * 8);
        float2 h0 = hp[0], h1 = hp[1], h2 = hp[2], h3 = hp[3];
        float s1 = 0.f, s2 = 0.f;
        s1 += h0.x; s2 += h0.x * h0.x; s1 += h0.y; s2 += h0.y * h0.y;
        s1 += h1.x; s2 += h1.x * h1.x; s1 += h1.y; s2 += h1.y * h1.y;
        s1 += h2.x; s2 += h2.x * h2.x; s1 += h2.y; s2 += h2.y * h2.y;
        s1 += h3.x; s2 += h3.x * h3.x; s1 += h3.y; s2 += h3.y * h3.y;
        s1 += __shfl_xor(s1, 8);  s2 += __shfl_xor(s2, 8);
        s1 += __shfl_xor(s1, 16); s2 += __shfl_xor(s2, 16);
        s1 += __shfl_xor(s1, 32); s2 += __shfl_xor(s2, 32);
        float mu = s1 * (1.f / 64.f);
        float var = s2 * (1.f / 64.f) - mu * mu;
        float rr = rsqrtf(var + 1e-5f);
        int kb = sub * 8;
        float hv[8] = {h0.x, h0.y, h1.x, h1.y, h2.x, h2.y, h3.x, h3.y};
        float sv[8], bv[8];
        ld8v<BF16>(ln1s, l * 64 + kb, sv);
        ld8v<BF16>(ln1b, l * 64 + kb, bv);
        float vv[8];
#pragma unroll
        for (int t2 = 0; t2 < 8; ++t2)
          vv[t2] = (hv[t2] - mu) * rr * sv[t2] + bv[t2];
        pk.x = pack_bf2(vv[0], vv[1]); pk.y = pack_bf2(vv[2], vv[3]);
        pk.z = pack_bf2(vv[4], vv[5]); pk.w = pack_bf2(vv[6], vv[7]);
      }
      int slot = (m >> 4) * 128 + (sub >> 2) * 64 + (sub & 3) * 16 + (m & 15);
      ((i32x4*)(sm + O_XNF))[slot] = pk;
    }
    __syncthreads();

    // ---- QKVG MFMA: 3 phases (QK / V / G) x 3 mt, specialized stores ----
    {
      const bf16x8* xnf = (const bf16x8*)(sm + O_XNF);
      // phase QK: waves 0-3 -> Q, waves 4-7 -> K; rotary fused, bf16 store
      {
        const bf16x8* wf = FRB + LB + ((w < 4) ? 0 : 512);
        unsigned short* dst = (w < 4) ? sQb : sKb;
        int ntl = w & 3;
        int n = ntl * 16 + ln;
        int j0 = n & 14;
        float sgn = (n & 1) ? 1.f : -1.f;
#pragma unroll
        for (int mt = 0; mt < 3; ++mt) {
          f32x4 acc = {0.f, 0.f, 0.f, 0.f};
          acc = MFMA(xnf[(mt * 2) * 64 + lane], wf[(ntl * 2) * 64 + lane], acc, 0, 0, 0);
          acc = MFMA(xnf[(mt * 2 + 1) * 64 + lane], wf[(ntl * 2 + 1) * 64 + lane], acc, 0, 0, 0);
          unsigned short rbf[4];
#pragma unroll
          for (int i = 0; i < 4; ++i) {
            float part = __shfl_xor(acc[i], 1);
            int t = lq * 4 + i - mt;   // (mt*16+lq*4+i) % 17, 16 == -1 mod 17
            if (t < 0) t += 17;
            float cv = sCos[t * 16 + j0], sv = sSin[t * 16 + j0];
            rbf[i] = cvt_bf(acc[i] * cv + part * (sgn * sv));
          }
          if (mt < 2) {
            unsigned short* p = dst + (mt * 16 + lq * 4) * 68 + n;
            p[0] = rbf[0]; p[68] = rbf[1]; p[136] = rbf[2]; p[204] = rbf[3];
          } else if (lq == 0) {
            unsigned short* p = dst + 32 * 68 + n;
            p[0] = rbf[0]; p[68] = rbf[1];
          }
        }
      }
      // phase V: transposed bf16 store, n = w*16+ln in 0..127
      {
        const bf16x8* wf = FRB + LB + 1024;
        int n = w * 16 + ln;
#pragma unroll
        for (int mt = 0; mt < 3; ++mt) {
          f32x4 acc = {0.f, 0.f, 0.f, 0.f};
          acc = MFMA(xnf[(mt * 2) * 64 + lane], wf[(w * 2) * 64 + lane], acc, 0, 0, 0);
          acc = MFMA(xnf[(mt * 2 + 1) * 64 + lane], wf[(w * 2 + 1) * 64 + lane], acc, 0, 0, 0);
          if (mt == 0) {  // img0, t = lq*4..+3: one b64 store
            uint2 uv;
            uv.x = pack_bf2(acc[0], acc[1]);
            uv.y = pack_bf2(acc[2], acc[3]);
            *(uint2*)(sVbT + n * 20 + lq * 4) = uv;
          } else if (mt == 1) {  // straddles image boundary
#pragma unroll
            for (int i = 0; i < 4; ++i) {
              int m = 16 + lq * 4 + i;
              int img = (m >= 17), t = m - img * 17;
              sVbT[img * 2560 + n * 20 + t] = cvt_bf(acc[i]);
            }
          } else if (lq == 0) {  // m=32,33 -> img1 t=15,16
            sVbT[2560 + n * 20 + 15] = cvt_bf(acc[0]);
            sVbT[2560 + n * 20 + 16] = cvt_bf(acc[1]);
          }
        }
      }
      // phase G: row-major bf16, n = w*16+ln in 0..127
      {
        const bf16x8* wf = FRB + LB + 2048;
        int n = w * 16 + ln;
#pragma unroll
        for (int mt = 0; mt < 3; ++mt) {
          f32x4 acc = {0.f, 0.f, 0.f, 0.f};
          acc = MFMA(xnf[(mt * 2) * 64 + lane], wf[(w * 2) * 64 + lane], acc, 0, 0, 0);
          acc = MFMA(xnf[(mt * 2 + 1) * 64 + lane], wf[(w * 2 + 1) * 64 + lane], acc, 0, 0, 0);
          if (mt < 2) {
            unsigned short* p = sGb + (mt * 16 + lq * 4) * 136 + n;
            p[0] = cvt_bf(acc[0]); p[136] = cvt_bf(acc[1]);
            p[272] = cvt_bf(acc[2]); p[408] = cvt_bf(acc[3]);
          } else if (lq == 0) {
            sGb[32 * 136 + n] = cvt_bf(acc[0]);
            sGb[33 * 136 + n] = cvt_bf(acc[1]);
          }
        }
      }
    }
    __syncthreads();

    // ---- fused scores+AV: bf16 frags direct from LDS, P stays in registers ----
    {
      int img = w >> 2, hh = w & 3;
      int cl = lane & 31, kh = lane >> 5;
      int tt = (cl < 17) ? cl : 16;  // clamp garbage rows (discarded at store)
      int m = img * 17 + tt;
      int off = m * 68 + hh * 16 + kh * 8;
      const uint2* qr = (const uint2*)(sQb + off);
      uint2 q0 = qr[0], q1 = qr[1];
      const uint2* kr = (const uint2*)(sKb + off);
      uint2 k0 = kr[0], k1 = kr[1];
      i32x4 ap; ap.x = (int)q0.x; ap.y = (int)q0.y; ap.z = (int)q1.x; ap.w = (int)q1.y;
      i32x4 bp; bp.x = (int)k0.x; bp.y = (int)k0.y; bp.z = (int)k1.x; bp.w = (int)k1.y;
      // V B-frag + tail (sVbT is stable since QKVG barrier)
      const unsigned short* vcol = sVbT + img * 2560 + (hh * 32 + cl) * 20 + kh * 8;
      uint2 v0 = ((const uint2*)vcol)[0], v1 = ((const uint2*)vcol)[1];
      i32x4 bpv; bpv.x = (int)v0.x; bpv.y = (int)v0.y; bpv.z = (int)v1.x; bpv.w = (int)v1.y;
      unsigned short v16 = sVbT[img * 2560 + (hh * 32 + cl) * 20 + 16];
      __syncthreads();  // all sQb/sKb reads done; sO (alias) writes follow

      f32x16 acc = {0.f, 0.f, 0.f, 0.f, 0.f, 0.f, 0.f, 0.f,
                    0.f, 0.f, 0.f, 0.f, 0.f, 0.f, 0.f, 0.f};
      acc = MFMA32(as_bf(bp), as_bf(ap), acc, 0, 0, 0);  // C[u][t]: lane cl holds row t=cl
      // dmask (incl 0.25) + causal; u=(r&3)+8*(r>>2)+4*kh
      const float* dmr = sDM + hh * 289 + tt * 17;
      float p[16];
#pragma unroll
      for (int r = 0; r < 16; ++r) {
        int u = (r & 3) + 8 * (r >> 2) + 4 * kh;
        p[r] = (u <= 16) ? acc[r] * dmr[u] : 0.f;
      }
      // denominator: own half + partner half
      float own = 0.f;
#pragma unroll
      for (int r = 0; r < 16; ++r) own += p[r];
      float den = fabsf(own + __shfl_xor(own, 32));
      if (den < 1.f) den = 1.f;
      den = __builtin_amdgcn_rcpf(den);
      // exchange halves for AV A-frag: kh0 needs u4..7 (partner p0..3), kh1 needs u8..11 (partner p4..7)
      float ex[4];
#pragma unroll
      for (int j = 0; j < 4; ++j)
        ex[j] = __shfl_xor((kh == 0) ? p[4 + j] : p[j], 32);
      float pd[8];
#pragma unroll
      for (int j = 0; j < 4; ++j) {
        pd[j]     = ((kh == 0) ? p[j]  : ex[j])     * den;  // kh0: u=j   ; kh1: u=8+j
        pd[4 + j] = ((kh == 0) ? ex[j] : p[4 + j])  * den;  // kh0: u=4+j ; kh1: u=12+j
      }
      i32x4 apv;
      apv.x = pack_bf2(pd[0], pd[1]); apv.y = pack_bf2(pd[2], pd[3]);
      apv.z = pack_bf2(pd[4], pd[5]); apv.w = pack_bf2(pd[6], pd[7]);
      f32x16 ao = {0.f, 0.f, 0.f, 0.f, 0.f, 0.f, 0.f, 0.f,
                   0.f, 0.f, 0.f, 0.f, 0.f, 0.f, 0.f, 0.f};
      ao = MFMA32(as_bf(apv), as_bf(bpv), ao, 0, 0, 0);
      i32x4 a1 = {0, 0, 0, 0}, b1v = {0, 0, 0, 0};
      if (kh == 0) {  // u=16 tail: p[8] holds u=16 for kh=0
        a1.x = (int)(unsigned)cvt_bf(p[8] * den);
        b1v.x = (int)(unsigned)v16;
      }
      ao = MFMA32(as_bf(a1), as_bf(b1v), ao, 0, 0, 0);
      int cg = hh * 32 + cl;
#pragma unroll
      for (int r = 0; r < 16; ++r) {
        int t = (r & 3) + 8 * (r >> 2) + 4 * kh;
        if (t < 17) sO[(img * 17 + t) * 134 + cg] = ao[r];
      }
    }
    __syncthreads();

    // ---- groupnorm (fused wave-local stats over 4 q-lanes) + silu -> OA frags ----
    for (int s = tid; s < 768; s += 512) {
      int mt = s >> 8, kt = (s >> 6) & 3, la = s & 63;
      int q = la >> 4, m = mt * 16 + (la & 15);
      int cb = kt * 32 + q * 8;
      i32x4 pk = {0, 0, 0, 0};
      if (m < 34) {
        const float2* op = (const float2*)(sO + m * 134 + cb);
        float2 o0 = op[0], o1 = op[1], o2 = op[2], o3 = op[3];
        float s1 = 0.f, s2 = 0.f;
        s1 += o0.x; s2 += o0.x * o0.x; s1 += o0.y; s2 += o0.y * o0.y;
        s1 += o1.x; s2 += o1.x * o1.x; s1 += o1.y; s2 += o1.y * o1.y;
        s1 += o2.x; s2 += o2.x * o2.x; s1 += o2.y; s2 += o2.y * o2.y;
        s1 += o3.x; s2 += o3.x * o3.x; s1 += o3.y; s2 += o3.y * o3.y;
        s1 += __shfl_xor(s1, 16); s2 += __shfl_xor(s2, 16);
        s1 += __shfl_xor(s1, 32); s2 += __shfl_xor(s2, 32);
        float mu = s1 * (1.f / 32.f);
        float var = s2 * (1.f / 32.f) - mu * mu;
        float rr = rsqrtf(var + 1e-5f);
        i32x4 gu = *(const i32x4*)(sGb + m * 136 + cb);
        float ov[8] = {o0.x, o0.y, o1.x, o1.y, o2.x, o2.y, o3.x, o3.y};
        float vv[8];
#pragma unroll
        for (int q2 = 0; q2 < 4; ++q2) {
          unsigned gw = (q2 == 0) ? (unsigned)gu.x : (q2 == 1) ? (unsigned)gu.y
                       : (q2 == 2) ? (unsigned)gu.z : (unsigned)gu.w;
          float2 gv = unpk(gw);
          float on0 = (ov[2 * q2] - mu) * rr;
          float on1 = (ov[2 * q2 + 1] - mu) * rr;
          vv[2 * q2]     = on0 * gv.x * __builtin_amdgcn_rcpf(1.f + __expf(-gv.x));
          vv[2 * q2 + 1] = on1 * gv.y * __builtin_amdgcn_rcpf(1.f + __expf(-gv.y));
        }
        pk.x = pack_bf2(vv[0], vv[1]); pk.y = pack_bf2(vv[2], vv[3]);
        pk.z = pack_bf2(vv[4], vv[5]); pk.w = pack_bf2(vv[6], vv[7]);
      }
      ((i32x4*)(sm + O_SCA))[s] = pk;
    }
    __syncthreads();

    // ---- Wo MFMA: 12 jobs / 8 waves; += residual ----
    {
      const bf16x8* oaf = (const bf16x8*)(sm + O_SCA);
      const bf16x8* wof = FRB + LB + 3072;
      for (int j = w; j < 12; j += 8) {
        int mt = j >> 2, nt = j & 3;
        f32x4 acc = {0.f, 0.f, 0.f, 0.f};
#pragma unroll
        for (int kt = 0; kt < 4; ++kt)
          acc = MFMA(oaf[(mt * 4 + kt) * 64 + lane], wof[(nt * 4 + kt) * 64 + lane], acc, 0, 0, 0);
        int n = nt * 16 + ln;
#pragma unroll
        for (int i = 0; i < 4; ++i) {
          int m = mt * 16 + lq * 4 + i;
          if (m < 34) sH[m * 66 + n] += acc[i];
        }
      }
    }
    __syncthreads();

    // ---- ln2: fused wave-local stats + A-frag build (bank-friendly lane map) ----
    if (tid < 320) {
      int la = tid & 63, wv = tid >> 6;
      int m = wv * 8 + (la & 7);
      int sub = ((la >> 3) & 3) + 4 * (la >> 5);
      i32x4 pk = {0, 0, 0, 0};
      if (m < 34) {
        const float2* hp = (const float2*)(sH + m * 66 + sub * 8);
        float2 h0 = hp[0], h1 = hp[1], h2 = hp[2], h3 = hp[3];
        float s1 = 0.f, s2 = 0.f;
        s1 += h0.x; s2 += h0.x * h0.x; s1 += h0.y; s2 += h0.y * h0.y;
        s1 += h1.x; s2 += h1.x * h1.x; s1 += h1.y; s2 += h1.y * h1.y;
        s1 += h2.x; s2 += h2.x * h2.x; s1 += h2.y; s2 += h2.y * h2.y;
        s1 += h3.x; s2 += h3.x * h3.x; s1 += h3.y; s2 += h3.y * h3.y;
        s1 += __shfl_xor(s1, 8);  s2 += __shfl_xor(s2, 8);
        s1 += __shfl_xor(s1, 16); s2 += __shfl_xor(s2, 16);
        s1 += __shfl_xor(s1, 32); s2 += __shfl_xor(s2, 32);
        float mu = s1 * (1.f / 64.f);
        float var = s2 * (1.f / 64.f) - mu * mu;
        float rr = rsqrtf(var + 1e-5f);
        int kb = sub * 8;
        float hv[8] = {h0.x, h0.y, h1.x, h1.y, h2.x, h2.y, h3.x, h3.y};
        float sv[8], bv[8];
        ld8v<BF16>(ln2s, l * 64 + kb, sv);
        ld8v<BF16>(ln2b, l * 64 + kb, bv);
        float vv[8];
#pragma unroll
        for (int t2 = 0; t2 < 8; ++t2)
          vv[t2] = (hv[t2] - mu) * rr * sv[t2] + bv[t2];
        pk.x = pack_bf2(vv[0], vv[1]); pk.y = pack_bf2(vv[2], vv[3]);
        pk.z = pack_bf2(vv[4], vv[5]); pk.w = pack_bf2(vv[6], vv[7]);
      }
      int slot = (m >> 4) * 128 + (sub >> 2) * 64 + (sub & 3) * 16 + (m & 15);
      ((i32x4*)(sm + O_XNF))[slot] = pk;
    }
    __syncthreads();

    // ---- FFN1 via MFMA: 3 jobs (mt), N=12 in one 16-tile, K=64; gelu at store ----
    if (w < 3) {
      const bf16x8* xnf = (const bf16x8*)(sm + O_XNF);
      const bf16x8* w1f = FRB + 35072 + l * 384;
      int mt = w;
      f32x4 acc = {0.f, 0.f, 0.f, 0.f};
#pragma unroll
      for (int kt = 0; kt < 2; ++kt)
        acc = MFMA(xnf[(mt * 2 + kt) * 64 + lane], w1f[kt * 64 + lane], acc, 0, 0, 0);
      if (ln < 12) {
        float b = ld<BF16>(b1, l * 12 + ln);
#pragma unroll
        for (int i = 0; i < 4; ++i) {
          int m = mt * 16 + lq * 4 + i;
          if (m < 34) {
            float a = acc[i] + b;
            float inner = 0.7978845608028654f * (a + 0.044715f * a * a * a);
            float e = __expf(2.f * inner);
            float th = 1.f - 2.f * __builtin_amdgcn_rcpf(e + 1.f);
            sFF[m * 12 + ln] = 0.5f * a * (1.f + th);
          }
        }
      }
    }
    __syncthreads();

    // ---- FFN2 via MFMA: 12 jobs (mt3 x nt4), K=32 (e padded); bias+residual at store ----
    {
      const bf16x8* w2f = FRB + 35072 + l * 384 + 128;
      for (int j = w; j < 12; j += 8) {
        int mt = j >> 2, nt = j & 3;
        i32x4 ap = {0, 0, 0, 0};
        int ma = mt * 16 + ln;
        if (ma < 34) {
          const float4* fp4 = (const float4*)(sFF + ma * 12);
          if (lq == 0) {
            float4 a = fp4[0], b4 = fp4[1];
            ap.x = pack_bf2(a.x, a.y); ap.y = pack_bf2(a.z, a.w);
            ap.z = pack_bf2(b4.x, b4.y); ap.w = pack_bf2(b4.z, b4.w);
          } else if (lq == 1) {
            float4 c4 = fp4[2];
            ap.x = pack_bf2(c4.x, c4.y); ap.y = pack_bf2(c4.z, c4.w);
          }
        }
        f32x4 acc = {0.f, 0.f, 0.f, 0.f};
        acc = MFMA(as_bf(ap), w2f[nt * 64 + lane], acc, 0, 0, 0);
        int n = nt * 16 + ln;
        float b = ld<BF16>(b2, l * 64 + n);
#pragma unroll
        for (int i = 0; i < 4; ++i) {
          int m = mt * 16 + lq * 4 + i;
          if (m < 34) sH[m * 66 + n] += acc[i] + b;
        }
      }
    }
    __syncthreads();
  }

  // ---- final: lnf (last token each image), neck, head ----
  if (tid < 2) {
    int m = tid * 17 + 16;
    float s1 = 0.f, s2 = 0.f;
    for (int d = 0; d < 64; ++d) {
      float v = sH[m * 66 + d];
      s1 += v; s2 += v * v;
    }
    float mu = s1 * (1.f / 64.f);
    float var = s2 * (1.f / 64.f) - mu * mu;
    sST[tid] = mu;
    sST[2 + tid] = rsqrtf(var + 1e-5f);
  }
  __syncthreads();
  if (tid < 32) {
    int img = tid >> 4, jn = tid & 15;
    int m = img * 17 + 16;
    float mu = sST[img], rr = sST[2 + img];
    float acc = ld<BF16>(neckb, jn);
    for (int d = 0; d < 64; ++d) {
      float yn = (sH[m * 66 + d] - mu) * rr * ld<BF16>(lnfs, d) + ld<BF16>(lnfb, d);
      acc += yn * ld<BF16>(neckw, d * 16 + jn);
    }
    sST[8 + img * 16 + jn] = acc;
  }
  __syncthreads();
  if (tid < 20) {
    int img = tid / 10, o = tid % 10;
    float acc = ld<BF16>(headb, o);
#pragma unroll
    for (int e = 0; e < 16; ++e) acc += sST[8 + img * 16 + e] * ld<BF16>(headw, e * 10 + o);
    if (BF16) {
      ((__hip_bfloat16*)out)[(img0 + img) * 10 + o] = __float2bfloat16(acc);
    } else {
      ((float*)out)[(img0 + img) * 10 + o] = acc;
    }
  }
}

extern "C" void kernel_launch(void* const* d_in, const int* in_sizes, int n_in,
                              void* d_out, int out_size, void* d_ws, size_t ws_size,
                              hipStream_t stream) {
  float* tab = (float*)d_ws;
  unsigned short* frag = (unsigned short*)((char*)d_ws + 8192);

  setup_tables<<<dim3(1), dim3(256), 0, stream>>>(tab, d_in[0]);

  const int prepBlocks = (FRAG_TOT + 255) / 256;
  prep_frags<false><<<dim3(prepBlocks), dim3(256), 0, stream>>>(
      d_in[1], d_in[5], d_in[6], d_in[7], d_in[8], d_in[9], d_in[12], d_in[14], tab, frag);
  prep_frags<true><<<dim3(prepBlocks), dim3(256), 0, stream>>>(
      d_in[1], d_in[5], d_in[6], d_in[7], d_in[8], d_in[9], d_in[12], d_in[14], tab, frag);

  const int B = in_sizes[0] / 3072;
  const int grid = B / 2;

  vit_fused<false><<<dim3(grid), dim3(512), 0, stream>>>(
      d_in[0], d_in[2], d_in[3], d_in[4], d_in[10], d_in[11], d_in[13],
      d_in[15], d_in[16], d_in[17], d_in[18], d_in[19], d_in[20], d_in[21],
      d_in[22], d_in[23], tab, frag, d_out);
  vit_fused<true><<<dim3(grid), dim3(512), 0, stream>>>(
      d_in[0], d_in[2], d_in[3], d_in[4], d_in[10], d_in[11], d_in[13],
      d_in[15], d_in[16], d_in[17], d_in[18], d_in[19], d_in[20], d_in[21],
      d_in[22], d_in[23], tab, frag, d_out);
}